// Round 5
// baseline (221.131 us; speedup 1.0000x reference)
//
#include <hip/hip_runtime.h>
#include <stdint.h>

#define B_   2
#define N_   16384
#define S_   4096
#define D2_  256
#define CIN_ 397
#define KP_  416      // Cin padded to 13*32 for MFMA K-slabs
#define C_   128
#define OC_  13
#define NCHUNK_ 16
#define CHS_ (S_ / NCHUNK_)       // 256 points per scan chunk
#define NCAND_ (NCHUNK_ * 3)      // 48 candidates per query
#define XQ_P 272                  // xq pitch in u16 (269 used, 16B-mult)

typedef unsigned short u16;
typedef unsigned int u32;
typedef short s16x8 __attribute__((ext_vector_type(8)));
typedef float f32x4 __attribute__((ext_vector_type(4)));
typedef float f32x2 __attribute__((ext_vector_type(2)));

#define MFMA16(a, b, c) __builtin_amdgcn_mfma_f32_16x16x32_bf16((a), (b), (c), 0, 0, 0)

__device__ __forceinline__ float b2f(u16 h) {
  union { unsigned int u; float f; } v; v.u = ((unsigned int)h) << 16; return v.f;
}
__device__ __forceinline__ u16 f2b(float f) {
  union { float f; unsigned int u; } v; v.f = f;
  unsigned int r = v.u + 0x7fffu + ((v.u >> 16) & 1u);
  return (u16)(r >> 16);
}

// 3-op branchless sorted-top3 insert on u32 keys (exact-equivalent to 5-op
// min/max version; v_med3_u32 has no builtin -> inline asm).
#define INS3M(k0, k1, k2, key)                                            \
  do {                                                                    \
    u32 _m1, _m2;                                                         \
    asm("v_med3_u32 %0, %1, %2, %3" : "=v"(_m1) : "v"(k0), "v"(k1), "v"(key)); \
    asm("v_med3_u32 %0, %1, %2, %3" : "=v"(_m2) : "v"(k1), "v"(k2), "v"(key)); \
    k0 = min(k0, key);                                                    \
    k1 = _m1;                                                             \
    k2 = _m2;                                                             \
  } while (0)

// ---------------------------------------------------------------------------
// setup_scan: ONE launch, 1088 blocks.
// [0,512): knn scan, 4 queries/thread (each LDS broadcast serves 8 distances
//          -- round-4 showed the scan was LDS-issue-bound, not VALU-bound).
// [512,1024): transpose points2 -> p2t (needed for interp gathers).
// [1024,1088): weight/bn prep.
// npT transpose is GONE: gemm_kernel now stages points1 through LDS itself.
// ---------------------------------------------------------------------------
__device__ __forceinline__ void transpose_body(
    const float* __restrict__ in, u16* __restrict__ out,
    int C, int S, int opitch, int b, int s0, int c0,
    float* __restrict__ tile, int tr, int tc4) {
  const float* ip = in + (size_t)b * C * S;
  u16* op = out + (size_t)b * S * opitch;
#pragma unroll
  for (int r = 0; r < 64; r += 16) {
    float4 v = *(const float4*)(ip + (size_t)(c0 + tr + r) * S + s0 + tc4);
    tile[(tr + r) * 65 + tc4 + 0] = v.x;
    tile[(tr + r) * 65 + tc4 + 1] = v.y;
    tile[(tr + r) * 65 + tc4 + 2] = v.z;
    tile[(tr + r) * 65 + tc4 + 3] = v.w;
  }
  __syncthreads();
#pragma unroll
  for (int r = 0; r < 64; r += 16) {
    ushort4 v;
    v.x = f2b(tile[(tc4 + 0) * 65 + tr + r]);
    v.y = f2b(tile[(tc4 + 1) * 65 + tr + r]);
    v.z = f2b(tile[(tc4 + 2) * 65 + tr + r]);
    v.w = f2b(tile[(tc4 + 3) * 65 + tr + r]);
    *(ushort4*)(op + (size_t)(s0 + tr + r) * opitch + c0 + tc4) = v;
  }
}

__global__ __launch_bounds__(256) void setup_scan_kernel(
    const float* __restrict__ xyz1, const float* __restrict__ xyz2,
    const float* __restrict__ points2,
    const float* __restrict__ fW, const float* __restrict__ fb,
    const float* __restrict__ fbn,
    const float* __restrict__ e1W, const float* __restrict__ e1b,
    const float* __restrict__ e1bn,
    const float* __restrict__ e2W, const float* __restrict__ e2b,
    const float* __restrict__ e2bn,
    const float* __restrict__ p1W, const float* __restrict__ p1b,
    const float* __restrict__ p1bn,
    const float* __restrict__ p2W, const float* __restrict__ p2b,
    const float* __restrict__ p2bn,
    u16* __restrict__ cand, u16* __restrict__ p2t,
    u16* __restrict__ Wf, u16* __restrict__ W1o,
    u16* __restrict__ W2o, u16* __restrict__ W3o,
    u16* __restrict__ Wp2, float* __restrict__ st) {
  __shared__ __align__(16) float smem[64 * 65];
  int id = blockIdx.x;
  int tid = threadIdx.x;

  if (id < 512) {
    // ---- knn scan: SoA LDS; 4 queries/thread; d = fma(-2, dot', n1) ----
    float* xs = smem;
    float* ys = smem + 256;
    float* zs = smem + 512;
    float* nw = smem + 768;
    int chunk = id & 15;
    int ny = (id >> 4) & 15;
    int b = id >> 8;
    int s0 = chunk * CHS_;
    const float* x2 = xyz2 + ((size_t)b * S_ + s0) * 3;
    {
      float xx = x2[tid * 3], yy = x2[tid * 3 + 1], zz = x2[tid * 3 + 2];
      xs[tid] = xx; ys[tid] = yy; zs[tid] = zz;
      nw[tid] = -0.5f * fmaf(xx, xx, fmaf(yy, yy, zz * zz));
    }
    __syncthreads();
    int nA = ny * 1024 + tid;     // queries nA + {0,256,512,768}
    float qx[4], qy[4], qz[4], n1[4];
#pragma unroll
    for (int q = 0; q < 4; ++q) {
      const float* x1 = xyz1 + ((size_t)b * N_ + nA + q * 256) * 3;
      qx[q] = x1[0]; qy[q] = x1[1]; qz[q] = x1[2];
      n1[q] = fmaf(qx[q], qx[q], fmaf(qy[q], qy[q], qz[q] * qz[q]));
    }
    u32 K[4][2][3];
#pragma unroll
    for (int q = 0; q < 4; ++q)
#pragma unroll
      for (int e = 0; e < 2; ++e)
#pragma unroll
        for (int r = 0; r < 3; ++r) K[q][e][r] = ~0u;
    f32x2 m2 = {-2.f, -2.f}, z2 = {0.f, 0.f};
#pragma unroll 2
    for (int s = 0; s < CHS_; s += 2) {
      f32x2 px = *(const f32x2*)(xs + s);
      f32x2 py = *(const f32x2*)(ys + s);
      f32x2 pz = *(const f32x2*)(zs + s);
      f32x2 pw = *(const f32x2*)(nw + s);
#pragma unroll
      for (int q = 0; q < 4; ++q) {
        f32x2 ax2 = {qx[q], qx[q]}, ay2 = {qy[q], qy[q]}, az2 = {qz[q], qz[q]};
        f32x2 n12 = {n1[q], n1[q]};
        f32x2 d = __builtin_elementwise_fma(az2, pz, pw);
        d = __builtin_elementwise_fma(ay2, py, d);
        d = __builtin_elementwise_fma(ax2, px, d);
        d = __builtin_elementwise_fma(m2, d, n12);
        d = __builtin_elementwise_max(d, z2);
        u32 k0 = (__float_as_uint(d[0]) & 0xFFFFFF00u) | (u32)s;
        u32 k1 = (__float_as_uint(d[1]) & 0xFFFFFF00u) | (u32)(s + 1);
        INS3M(K[q][0][0], K[q][0][1], K[q][0][2], k0);
        INS3M(K[q][1][0], K[q][1][1], K[q][1][2], k1);
      }
    }
#pragma unroll
    for (int q = 0; q < 4; ++q) {
      INS3M(K[q][0][0], K[q][0][1], K[q][0][2], K[q][1][0]);
      INS3M(K[q][0][0], K[q][0][1], K[q][0][2], K[q][1][1]);
      INS3M(K[q][0][0], K[q][0][1], K[q][0][2], K[q][1][2]);
      u16* co = cand + ((size_t)(b * N_ + nA + q * 256)) * NCAND_ + chunk * 3;
      co[0] = (u16)((K[q][0][0] & 0xFFu) + s0);
      co[1] = (u16)((K[q][0][1] & 0xFFu) + s0);
      co[2] = (u16)((K[q][0][2] & 0xFFu) + s0);
    }
    return;
  }

  int tr = tid >> 4;
  int tc4 = (tid & 15) * 4;
  if (id < 1024) {
    int id2 = id - 512;
    int sx = id2 & 63, sy = (id2 >> 6) & 3, b = id2 >> 8;
    transpose_body(points2, p2t, 256, S_, 256, b, sx * 64, sy * 64, smem, tr, tc4);
    return;
  }
  int t = (id - 1024) * 256 + tid;
  int stride = 64 * 256;
  for (int i = t; i < 128 * KP_; i += stride) {
    int m = i / KP_, k = i - m * KP_;
    Wf[i] = (k < CIN_) ? f2b(fW[m * CIN_ + k]) : (u16)0;
  }
  for (int i = t; i < 128 * 128; i += stride) {
    W1o[i] = f2b(e1W[i]);
    W2o[i] = f2b(e2W[i]);
    W3o[i] = f2b(p1W[i]);
  }
  for (int i = t; i < 16 * 128; i += stride) {
    int m = i >> 7;
    Wp2[i] = (m < OC_) ? f2b(p2W[i]) : (u16)0;
  }
  for (int i = t; i < 5 * 128; i += stride) {
    int sg = i >> 7, c = i & 127;
    const float* bn; const float* bc; int Cc = 128;
    switch (sg) {
      case 0: bn = fbn;  bc = fb;  break;
      case 1: bn = e1bn; bc = e1b; break;
      case 2: bn = e2bn; bc = e2b; break;
      case 3: bn = p1bn; bc = p1b; break;
      default: bn = p2bn; bc = p2b; Cc = OC_; break;
    }
    float s = 0.f, tt = 0.f;
    if (c < Cc) {
      float g  = bn[0 * Cc + c], be = bn[1 * Cc + c];
      float mu = bn[2 * Cc + c], vv = bn[3 * Cc + c];
      float inv = 1.0f / sqrtf(vv + 1e-5f);
      s = g * inv;
      tt = (bc[c] - mu) * s + be;
    }
    st[sg * 256 + c] = s;
    st[sg * 256 + 128 + c] = tt;
  }
}

// ---------------------------------------------------------------------------
// f64 lexicographic (d, idx) top-3 insert -- matches stable top_k semantics
// ---------------------------------------------------------------------------
__device__ __forceinline__ void ins3(double d, int i,
                                     double& D0, double& D1, double& D2,
                                     int& I0, int& I1, int& I2) {
  if ((d < D2) || (d == D2 && i < I2)) {
    if ((d < D1) || (d == D1 && i < I1)) {
      D2 = D1; I2 = I1;
      if ((d < D0) || (d == D0 && i < I0)) { D1 = D0; I1 = I0; D0 = d; I0 = i; }
      else                                  { D1 = d; I1 = i; }
    } else { D2 = d; I2 = i; }
  }
}

// ---------------------------------------------------------------------------
// interp_kernel: gather/bandwidth phase (unchanged from round 3/4).
// ---------------------------------------------------------------------------
__global__ __launch_bounds__(256) void interp_kernel(
    const float* __restrict__ xyz1, const float* __restrict__ xyz2,
    const u16* __restrict__ cand, const u16* __restrict__ p2t,
    const float* __restrict__ last_pred, u16* __restrict__ xq) {
  __shared__ int   iS[32][3];
  __shared__ float wS[32][3];
  int id = blockIdx.x;
  int b = id >> 9;
  int n0 = (id & 511) * 32;
  int tid = threadIdx.x;

  // ---- phase 1: refine ----
  {
#pragma clang fp contract(off)
    int qi = tid >> 3, part = tid & 7;
    int qg = b * N_ + n0 + qi;
    const u16* ci = cand + (size_t)qg * NCAND_ + part * 6;
    const float* x2b = xyz2 + (size_t)b * S_ * 3;
    int ii[6];
#pragma unroll
    for (int j = 0; j < 6; ++j) ii[j] = ci[j];
    float pcx[6], pcy[6], pcz[6];
#pragma unroll
    for (int j = 0; j < 6; ++j) {
      const float* p = x2b + (size_t)ii[j] * 3;
      pcx[j] = p[0]; pcy[j] = p[1]; pcz[j] = p[2];
    }
    const float* x1 = xyz1 + (size_t)qg * 3;
    double ax = x1[0], ay = x1[1], az = x1[2];
    double n1 = (ax * ax + ay * ay) + az * az;
    double D0 = 1e300, D1 = 1e300, D2v = 1e300;
    int I0 = 2147483647, I1 = 2147483647, I2 = 2147483647;
#pragma unroll
    for (int j = 0; j < 6; ++j) {
      double px = pcx[j], py = pcy[j], pz = pcz[j];
      double n2 = (px * px + py * py) + pz * pz;
      double dot = (ax * px + ay * py) + az * pz;
      double d = (n1 + n2) - 2.0 * dot;
      ins3(d, ii[j], D0, D1, D2v, I0, I1, I2);
    }
#pragma unroll
    for (int r = 0; r < 3; ++r) {
      int m = 1 << r;
      double e0 = __shfl_xor(D0, m);
      double e1 = __shfl_xor(D1, m);
      double e2 = __shfl_xor(D2v, m);
      int j0 = __shfl_xor(I0, m);
      int j1 = __shfl_xor(I1, m);
      int j2 = __shfl_xor(I2, m);
      ins3(e0, j0, D0, D1, D2v, I0, I1, I2);
      ins3(e1, j1, D0, D1, D2v, I0, I1, I2);
      ins3(e2, j2, D0, D1, D2v, I0, I1, I2);
    }
    if (part == 0) {
      double r0 = 1.0 / (D0 + 1e-8);
      double r1 = 1.0 / (D1 + 1e-8);
      double r2 = 1.0 / (D2v + 1e-8);
      double sum = (r0 + r1) + r2;
      wS[qi][0] = (float)(r0 / sum);
      wS[qi][1] = (float)(r1 / sum);
      wS[qi][2] = (float)(r2 / sum);
      iS[qi][0] = I0; iS[qi][1] = I1; iS[qi][2] = I2;
    }
  }
  __syncthreads();

  // ---- phase 2: interp, one (query, 32-channel group) per lane ----
  int wv = tid >> 6, lane = tid & 63;
  int q = wv * 8 + (lane >> 3);    // local query 0..31
  int cg = lane & 7;               // channel group: ch [cg*32, cg*32+32)
  int n = n0 + q;
  int i0 = iS[q][0], i1 = iS[q][1], i2 = iS[q][2];
  float w0 = wS[q][0], w1 = wS[q][1], w2 = wS[q][2];
  const u16* p2b = p2t + (size_t)b * S_ * D2_;
  const u16* r0p = p2b + (size_t)i0 * D2_ + cg * 32;
  const u16* r1p = p2b + (size_t)i1 * D2_ + cg * 32;
  const u16* r2p = p2b + (size_t)i2 * D2_ + cg * 32;
  u16* xrow = xq + (size_t)(b * N_ + n) * XQ_P;
#pragma unroll
  for (int j = 0; j < 8; ++j) {
    ushort4 a = *(const ushort4*)(r0p + j * 4);
    ushort4 e = *(const ushort4*)(r1p + j * 4);
    ushort4 c = *(const ushort4*)(r2p + j * 4);
    ushort4 v;
    v.x = f2b((w0 * b2f(a.x) + w1 * b2f(e.x)) + w2 * b2f(c.x));
    v.y = f2b((w0 * b2f(a.y) + w1 * b2f(e.y)) + w2 * b2f(c.y));
    v.z = f2b((w0 * b2f(a.z) + w1 * b2f(e.z)) + w2 * b2f(c.z));
    v.w = f2b((w0 * b2f(a.w) + w1 * b2f(e.w)) + w2 * b2f(c.w));
    *(ushort4*)(xrow + cg * 32 + j * 4) = v;
  }
  if (cg == 0) {
    const float* lpb = last_pred + (size_t)b * S_ * OC_;
    u16 pv[16];
#pragma unroll
    for (int c = 0; c < 16; ++c) pv[c] = 0;
#pragma unroll
    for (int c = 0; c < OC_; ++c) {
      float l0 = lpb[(size_t)i0 * OC_ + c];
      float l1 = lpb[(size_t)i1 * OC_ + c];
      float l2 = lpb[(size_t)i2 * OC_ + c];
      pv[c] = f2b((w0 * l0 + w1 * l1) + w2 * l2);
    }
#pragma unroll
    for (int c4 = 0; c4 < 4; ++c4) {
      *(ushort4*)(xrow + 256 + c4 * 4) =
          make_ushort4(pv[c4 * 4], pv[c4 * 4 + 1], pv[c4 * 4 + 2], pv[c4 * 4 + 3]);
    }
  }
}

// ---------------------------------------------------------------------------
// gemm_kernel: pure compute phase. Round-5 change: npT is gone -- the 32x128
// points1 tile is staged through xb1 (dead during stage 1) with on-the-fly
// f32->bf16, then stage-1 k<128 B-fragments read from LDS. Same bytes the
// kernel would have read from npT, minus the whole setup transpose pass.
// ---------------------------------------------------------------------------
__device__ __forceinline__ void gemm32(const u16* __restrict__ W, const u16* xb,
                                       int l15, int lq, int wv, f32x4 acc[2][2]) {
#pragma unroll
  for (int mtl = 0; mtl < 2; ++mtl) {
    acc[mtl][0] = (f32x4){0.f, 0.f, 0.f, 0.f};
    acc[mtl][1] = (f32x4){0.f, 0.f, 0.f, 0.f};
  }
#pragma unroll
  for (int ks = 0; ks < 4; ++ks) {
    int ko = ks * 32 + lq * 8;
    s16x8 b0 = *(const s16x8*)(xb + l15 * 136 + ko);
    s16x8 b1 = *(const s16x8*)(xb + (16 + l15) * 136 + ko);
#pragma unroll
    for (int mtl = 0; mtl < 2; ++mtl) {
      s16x8 a = *(const s16x8*)(W + (size_t)((wv * 2 + mtl) * 16 + l15) * 128 + ko);
      acc[mtl][0] = MFMA16(a, b0, acc[mtl][0]);
      acc[mtl][1] = MFMA16(a, b1, acc[mtl][1]);
    }
  }
}

__global__ __launch_bounds__(256, 4) void gemm_kernel(
    const float* __restrict__ points1, const u16* __restrict__ xq,
    const u16* __restrict__ Wf,
    const u16* __restrict__ W1, const u16* __restrict__ W2,
    const u16* __restrict__ W3, const u16* __restrict__ Wp2,
    const float* __restrict__ st, float* __restrict__ out) {
  __shared__ __align__(16) u16 xb0[32 * 136];
  __shared__ __align__(16) u16 xb1[32 * 136];
  int b = blockIdx.y;
  int n0 = blockIdx.x * 32;
  int tid = threadIdx.x;
  int wv = tid >> 6, lane = tid & 63;
  int l15 = lane & 15, lq = lane >> 4;
  f32x4 acc[2][2];

  // ---- stage 0: stage points1 tile [c=128][n=32] -> xb1[n][c] bf16 ----
  {
    int n4 = (tid & 7) * 4;
    int cb = tid >> 3;             // 0..31
    const float* p1b = points1 + (size_t)b * C_ * N_;
#pragma unroll
    for (int rep = 0; rep < 4; ++rep) {
      int c = cb + rep * 32;
      float4 v = *(const float4*)(p1b + (size_t)c * N_ + n0 + n4);
      xb1[(n4 + 0) * 136 + c] = f2b(v.x);
      xb1[(n4 + 1) * 136 + c] = f2b(v.y);
      xb1[(n4 + 2) * 136 + c] = f2b(v.z);
      xb1[(n4 + 3) * 136 + c] = f2b(v.w);
    }
  }
  __syncthreads();

  // ---- stage 1: fuse (K=416): k<128 from xb1 (staged points1), rest xq ----
#pragma unroll
  for (int mtl = 0; mtl < 2; ++mtl) {
    acc[mtl][0] = (f32x4){0.f, 0.f, 0.f, 0.f};
    acc[mtl][1] = (f32x4){0.f, 0.f, 0.f, 0.f};
  }
  {
#pragma unroll 2
    for (int ks = 0; ks < 4; ++ks) {
      int ko = ks * 32 + lq * 8;
      s16x8 bf0 = *(const s16x8*)(&xb1[l15 * 136 + ko]);
      s16x8 bf1 = *(const s16x8*)(&xb1[(16 + l15) * 136 + ko]);
#pragma unroll
      for (int mtl = 0; mtl < 2; ++mtl) {
        s16x8 a = *(const s16x8*)(Wf + (size_t)((wv * 2 + mtl) * 16 + l15) * KP_ + ko);
        acc[mtl][0] = MFMA16(a, bf0, acc[mtl][0]);
        acc[mtl][1] = MFMA16(a, bf1, acc[mtl][1]);
      }
    }
    const u16* qrow0 = xq + ((size_t)(b * N_ + n0 + l15)) * XQ_P;
    const u16* qrow1 = qrow0 + (size_t)16 * XQ_P;
#pragma unroll 3
    for (int ks = 0; ks < 9; ++ks) {
      int col = ks * 32 + lq * 8;
      s16x8 bf0 = {0, 0, 0, 0, 0, 0, 0, 0};
      s16x8 bf1 = {0, 0, 0, 0, 0, 0, 0, 0};
      if (ks < 8 || lq < 2) {     // cols >= 272 are implicit zeros (W also 0)
        bf0 = *(const s16x8*)(qrow0 + col);
        bf1 = *(const s16x8*)(qrow1 + col);
      }
#pragma unroll
      for (int mtl = 0; mtl < 2; ++mtl) {
        s16x8 a = *(const s16x8*)(Wf + (size_t)((wv * 2 + mtl) * 16 + l15) * KP_ + 128 + col);
        acc[mtl][0] = MFMA16(a, bf0, acc[mtl][0]);
        acc[mtl][1] = MFMA16(a, bf1, acc[mtl][1]);
      }
    }
  }
  __syncthreads();   // xb1 reads done (stage 2 will overwrite it)
#pragma unroll
  for (int mtl = 0; mtl < 2; ++mtl) {
    int m4 = (wv * 2 + mtl) * 16 + lq * 4;
    f32x4 sc = *(const f32x4*)(st + 0 * 256 + m4);
    f32x4 bi = *(const f32x4*)(st + 0 * 256 + 128 + m4);
#pragma unroll
    for (int nt = 0; nt < 2; ++nt) {
      int n_l = nt * 16 + l15;
      ushort4 v;
      v.x = f2b(fmaxf(acc[mtl][nt][0] * sc[0] + bi[0], 0.f));
      v.y = f2b(fmaxf(acc[mtl][nt][1] * sc[1] + bi[1], 0.f));
      v.z = f2b(fmaxf(acc[mtl][nt][2] * sc[2] + bi[2], 0.f));
      v.w = f2b(fmaxf(acc[mtl][nt][3] * sc[3] + bi[3], 0.f));
      *(ushort4*)(&xb0[n_l * 136 + m4]) = v;
    }
  }
  __syncthreads();

  // ---- stage 2: ext1 (K=128), xb0 -> xb1 ----
  gemm32(W1, xb0, l15, lq, wv, acc);
#pragma unroll
  for (int mtl = 0; mtl < 2; ++mtl) {
    int m4 = (wv * 2 + mtl) * 16 + lq * 4;
    f32x4 sc = *(const f32x4*)(st + 1 * 256 + m4);
    f32x4 bi = *(const f32x4*)(st + 1 * 256 + 128 + m4);
#pragma unroll
    for (int nt = 0; nt < 2; ++nt) {
      int n_l = nt * 16 + l15;
      ushort4 v;
      v.x = f2b(fmaxf(acc[mtl][nt][0] * sc[0] + bi[0], 0.f));
      v.y = f2b(fmaxf(acc[mtl][nt][1] * sc[1] + bi[1], 0.f));
      v.z = f2b(fmaxf(acc[mtl][nt][2] * sc[2] + bi[2], 0.f));
      v.w = f2b(fmaxf(acc[mtl][nt][3] * sc[3] + bi[3], 0.f));
      *(ushort4*)(&xb1[n_l * 136 + m4]) = v;
    }
  }
  __syncthreads();

  // ---- stage 3: ext2 (K=128), xb1 -> xb0, + residual(xb0), store out0 ----
  gemm32(W2, xb1, l15, lq, wv, acc);
#pragma unroll
  for (int mtl = 0; mtl < 2; ++mtl) {
    int m4 = (wv * 2 + mtl) * 16 + lq * 4;
    f32x4 sc = *(const f32x4*)(st + 2 * 256 + m4);
    f32x4 bi = *(const f32x4*)(st + 2 * 256 + 128 + m4);
#pragma unroll
    for (int nt = 0; nt < 2; ++nt) {
      int n_l = nt * 16 + l15;
      int n_g = n0 + n_l;
      ushort4 xp = *(const ushort4*)(&xb0[n_l * 136 + m4]);
      float v0 = fmaxf(acc[mtl][nt][0] * sc[0] + bi[0] + b2f(xp.x), 0.f);
      float v1 = fmaxf(acc[mtl][nt][1] * sc[1] + bi[1] + b2f(xp.y), 0.f);
      float v2 = fmaxf(acc[mtl][nt][2] * sc[2] + bi[2] + b2f(xp.z), 0.f);
      float v3 = fmaxf(acc[mtl][nt][3] * sc[3] + bi[3] + b2f(xp.w), 0.f);
      ushort4 v;
      v.x = f2b(v0); v.y = f2b(v1); v.z = f2b(v2); v.w = f2b(v3);
      *(ushort4*)(&xb0[n_l * 136 + m4]) = v;
      out[((size_t)(b * C_ + m4 + 0)) * N_ + n_g] = v0;
      out[((size_t)(b * C_ + m4 + 1)) * N_ + n_g] = v1;
      out[((size_t)(b * C_ + m4 + 2)) * N_ + n_g] = v2;
      out[((size_t)(b * C_ + m4 + 3)) * N_ + n_g] = v3;
    }
  }
  __syncthreads();

  // ---- stage 4: pred1 (K=128), xb0 -> xb1, store out1 ([B][N][128]) ----
  gemm32(W3, xb0, l15, lq, wv, acc);
  {
    float* out1 = out + (size_t)B_ * C_ * N_;
#pragma unroll
    for (int mtl = 0; mtl < 2; ++mtl) {
      int m4 = (wv * 2 + mtl) * 16 + lq * 4;
      f32x4 sc = *(const f32x4*)(st + 3 * 256 + m4);
      f32x4 bi = *(const f32x4*)(st + 3 * 256 + 128 + m4);
#pragma unroll
      for (int nt = 0; nt < 2; ++nt) {
        int n_l = nt * 16 + l15;
        int n_g = n0 + n_l;
        float v0 = fmaxf(acc[mtl][nt][0] * sc[0] + bi[0], 0.f);
        float v1 = fmaxf(acc[mtl][nt][1] * sc[1] + bi[1], 0.f);
        float v2 = fmaxf(acc[mtl][nt][2] * sc[2] + bi[2], 0.f);
        float v3 = fmaxf(acc[mtl][nt][3] * sc[3] + bi[3], 0.f);
        ushort4 v;
        v.x = f2b(v0); v.y = f2b(v1); v.z = f2b(v2); v.w = f2b(v3);
        *(ushort4*)(&xb1[n_l * 136 + m4]) = v;
        float4 o4 = make_float4(v0, v1, v2, v3);
        *(float4*)(out1 + ((size_t)(b * N_ + n_g)) * 128 + m4) = o4;
      }
    }
  }
  __syncthreads();

  // ---- stage 5: pred2 (M=13 pad 16, K=128): waves 0,1 each do one nt ----
  if (wv < 2) {
    f32x4 a2 = (f32x4){0.f, 0.f, 0.f, 0.f};
#pragma unroll
    for (int ks = 0; ks < 4; ++ks) {
      int ko = ks * 32 + lq * 8;
      s16x8 b0 = *(const s16x8*)(&xb1[(wv * 16 + l15) * 136 + ko]);
      s16x8 a = *(const s16x8*)(Wp2 + (size_t)l15 * 128 + ko);
      a2 = MFMA16(a, b0, a2);
    }
    float* out2 = out + (size_t)B_ * C_ * N_ + (size_t)B_ * N_ * 128;
    f32x4 sc = *(const f32x4*)(st + 4 * 256 + lq * 4);
    f32x4 bi = *(const f32x4*)(st + 4 * 256 + 128 + lq * 4);
    int n_g = n0 + wv * 16 + l15;
#pragma unroll
    for (int r = 0; r < 4; ++r) {
      int m = lq * 4 + r;
      if (m < OC_) {
        out2[((size_t)(b * N_ + n_g)) * OC_ + m] =
            fmaxf(a2[r] * sc[r] + bi[r], 0.f);
      }
    }
  }
}

// ---------------------------------------------------------------------------
extern "C" void kernel_launch(void* const* d_in, const int* in_sizes, int n_in,
                              void* d_out, int out_size, void* d_ws, size_t ws_size,
                              hipStream_t stream) {
  const float* xyz1      = (const float*)d_in[0];
  const float* xyz2      = (const float*)d_in[1];
  const float* points1   = (const float*)d_in[2];
  const float* points2   = (const float*)d_in[3];
  const float* last_pred = (const float*)d_in[4];
  const float* fuse_W    = (const float*)d_in[5];
  const float* fuse_b    = (const float*)d_in[6];
  const float* fuse_bn   = (const float*)d_in[7];
  const float* ext1_W    = (const float*)d_in[8];
  const float* ext1_b    = (const float*)d_in[9];
  const float* ext1_bn   = (const float*)d_in[10];
  const float* ext2_W    = (const float*)d_in[11];
  const float* ext2_b    = (const float*)d_in[12];
  const float* ext2_bn   = (const float*)d_in[13];
  const float* pred1_W   = (const float*)d_in[14];
  const float* pred1_b   = (const float*)d_in[15];
  const float* pred1_bn  = (const float*)d_in[16];
  const float* pred2_W   = (const float*)d_in[17];
  const float* pred2_b   = (const float*)d_in[18];
  const float* pred2_bn  = (const float*)d_in[19];

  char* ws = (char*)d_ws;
  u16*   p2t  = (u16*)(ws + 0);                // 2*4096*256*2  =  4,194,304
  u16*   cand = (u16*)(ws + 4194304);          // 2*16384*48*2  =  3,145,728
  u16*   Wf   = (u16*)(ws + 7340032);          // 128*416*2     =    106,496
  u16*   W1   = (u16*)(ws + 7446528);          // 128*128*2     =     32,768
  u16*   W2   = (u16*)(ws + 7479296);          //                     32,768
  u16*   W3   = (u16*)(ws + 7512064);          //                     32,768
  u16*   Wp2  = (u16*)(ws + 7544832);          // 16*128*2      =      4,096
  float* st   = (float*)(ws + 7548928);        // 5*256*4       =      5,120
  u16*   xq   = (u16*)(ws + 7554048);          // 2*16384*272*2 = 17,825,792
                                               // total 25,379,840 B

  setup_scan_kernel<<<dim3(1088), dim3(256), 0, stream>>>(
      xyz1, xyz2, points2,
      fuse_W, fuse_b, fuse_bn, ext1_W, ext1_b, ext1_bn, ext2_W, ext2_b, ext2_bn,
      pred1_W, pred1_b, pred1_bn, pred2_W, pred2_b, pred2_bn,
      cand, p2t, Wf, W1, W2, W3, Wp2, st);

  interp_kernel<<<dim3(1024), dim3(256), 0, stream>>>(
      xyz1, xyz2, cand, p2t, last_pred, xq);

  gemm_kernel<<<dim3(N_ / 32, B_), dim3(256), 0, stream>>>(
      points1, xq, Wf, W1, W2, W3, Wp2, st, (float*)d_out);
}

// Round 6
// 218.876 us; speedup vs baseline: 1.0103x; 1.0103x over previous
//
#include <hip/hip_runtime.h>
#include <stdint.h>

#define B_   2
#define N_   16384
#define S_   4096
#define D2_  256
#define CIN_ 397
#define KP_  416      // Cin padded to 13*32 for MFMA K-slabs
#define C_   128
#define OC_  13
#define NCHUNK_ 16
#define CHS_ (S_ / NCHUNK_)       // 256 points per scan chunk
#define XQ_P 272                  // xq pitch in u16 (269 used, 16B-mult)

typedef unsigned short u16;
typedef unsigned int u32;
typedef short s16x8 __attribute__((ext_vector_type(8)));
typedef float f32x4 __attribute__((ext_vector_type(4)));
typedef float f32x2 __attribute__((ext_vector_type(2)));

#define MFMA16(a, b, c) __builtin_amdgcn_mfma_f32_16x16x32_bf16((a), (b), (c), 0, 0, 0)

__device__ __forceinline__ float b2f(u16 h) {
  union { unsigned int u; float f; } v; v.u = ((unsigned int)h) << 16; return v.f;
}
__device__ __forceinline__ u16 f2b(float f) {
  union { float f; unsigned int u; } v; v.f = f;
  unsigned int r = v.u + 0x7fffu + ((v.u >> 16) & 1u);
  return (u16)(r >> 16);
}

// 3-op branchless sorted-top3 insert on u32 keys (exact-equivalent to 5-op
// min/max version; v_med3_u32 has no builtin -> inline asm).
#define INS3M(k0, k1, k2, key)                                            \
  do {                                                                    \
    u32 _m1, _m2;                                                         \
    asm("v_med3_u32 %0, %1, %2, %3" : "=v"(_m1) : "v"(k0), "v"(k1), "v"(key)); \
    asm("v_med3_u32 %0, %1, %2, %3" : "=v"(_m2) : "v"(k1), "v"(k2), "v"(key)); \
    k0 = min(k0, key);                                                    \
    k1 = _m1;                                                             \
    k2 = _m2;                                                             \
  } while (0)

#define SHL(v) __builtin_shufflevector((v), (v), 0, 1)
#define SHH(v) __builtin_shufflevector((v), (v), 2, 3)

// ---------------------------------------------------------------------------
// setup_scan: ONE launch, 1088 blocks.
// [0,512): knn scan, 4 queries/thread. Round-6: point data consumed from
//   explicit double-buffered register blocks (8 points = 8 wave-uniform
//   ds_read_b128, ONE lgkmcnt wait) -- rounds 3-5 were pinned at 47.5us by
//   per-pair load->wait->use LDS latency serialization, invariant under all
//   VALU/occupancy changes.
// [512,1024): transpose points2 -> p2t. [1024,1088): weight/bn prep.
// cand is chunk-major ushort4-padded: coalesced full-line writes (round-5
// WRITE_SIZE showed ~15MB of partial-line RMW amplification).
// ---------------------------------------------------------------------------
__device__ __forceinline__ void transpose_body(
    const float* __restrict__ in, u16* __restrict__ out,
    int C, int S, int opitch, int b, int s0, int c0,
    float* __restrict__ tile, int tr, int tc4) {
  const float* ip = in + (size_t)b * C * S;
  u16* op = out + (size_t)b * S * opitch;
#pragma unroll
  for (int r = 0; r < 64; r += 16) {
    float4 v = *(const float4*)(ip + (size_t)(c0 + tr + r) * S + s0 + tc4);
    tile[(tr + r) * 65 + tc4 + 0] = v.x;
    tile[(tr + r) * 65 + tc4 + 1] = v.y;
    tile[(tr + r) * 65 + tc4 + 2] = v.z;
    tile[(tr + r) * 65 + tc4 + 3] = v.w;
  }
  __syncthreads();
#pragma unroll
  for (int r = 0; r < 64; r += 16) {
    ushort4 v;
    v.x = f2b(tile[(tc4 + 0) * 65 + tr + r]);
    v.y = f2b(tile[(tc4 + 1) * 65 + tr + r]);
    v.z = f2b(tile[(tc4 + 2) * 65 + tr + r]);
    v.w = f2b(tile[(tc4 + 3) * 65 + tr + r]);
    *(ushort4*)(op + (size_t)(s0 + tr + r) * opitch + c0 + tc4) = v;
  }
}

__global__ __launch_bounds__(256) void setup_scan_kernel(
    const float* __restrict__ xyz1, const float* __restrict__ xyz2,
    const float* __restrict__ points2,
    const float* __restrict__ fW, const float* __restrict__ fb,
    const float* __restrict__ fbn,
    const float* __restrict__ e1W, const float* __restrict__ e1b,
    const float* __restrict__ e1bn,
    const float* __restrict__ e2W, const float* __restrict__ e2b,
    const float* __restrict__ e2bn,
    const float* __restrict__ p1W, const float* __restrict__ p1b,
    const float* __restrict__ p1bn,
    const float* __restrict__ p2W, const float* __restrict__ p2b,
    const float* __restrict__ p2bn,
    u16* __restrict__ cand, u16* __restrict__ p2t,
    u16* __restrict__ Wf, u16* __restrict__ W1o,
    u16* __restrict__ W2o, u16* __restrict__ W3o,
    u16* __restrict__ Wp2, float* __restrict__ st) {
  __shared__ __align__(16) float smem[64 * 65];
  int id = blockIdx.x;
  int tid = threadIdx.x;

  if (id < 512) {
    // ---- knn scan: SoA LDS (272-spaced, 8-float pad for prefetch
    //      overrun); 4 queries/thread; d = fma(-2, dot', n1) ----
    float* xs = smem;
    float* ys = smem + 272;
    float* zs = smem + 544;
    float* nw = smem + 816;
    int chunk = id & 15;
    int ny = (id >> 4) & 15;
    int b = id >> 8;
    int s0 = chunk * CHS_;
    const float* x2 = xyz2 + ((size_t)b * S_ + s0) * 3;
    {
      float xx = x2[tid * 3], yy = x2[tid * 3 + 1], zz = x2[tid * 3 + 2];
      xs[tid] = xx; ys[tid] = yy; zs[tid] = zz;
      nw[tid] = -0.5f * fmaf(xx, xx, fmaf(yy, yy, zz * zz));
    }
    __syncthreads();
    int nA = ny * 1024 + tid;     // queries nA + {0,256,512,768}
    float qx[4], qy[4], qz[4], n1[4];
#pragma unroll
    for (int q = 0; q < 4; ++q) {
      const float* x1 = xyz1 + ((size_t)b * N_ + nA + q * 256) * 3;
      qx[q] = x1[0]; qy[q] = x1[1]; qz[q] = x1[2];
      n1[q] = fmaf(qx[q], qx[q], fmaf(qy[q], qy[q], qz[q] * qz[q]));
    }
    u32 K[4][2][3];
#pragma unroll
    for (int q = 0; q < 4; ++q)
#pragma unroll
      for (int e = 0; e < 2; ++e)
#pragma unroll
        for (int r = 0; r < 3; ++r) K[q][e][r] = ~0u;
    f32x2 m2 = {-2.f, -2.f}, z2 = {0.f, 0.f};

#define LOAD8(X0, X1, Y0, Y1, Z0, Z1, W0, W1, sb)                         \
    do {                                                                  \
      X0 = *(const f32x4*)(xs + (sb));  X1 = *(const f32x4*)(xs + (sb) + 4); \
      Y0 = *(const f32x4*)(ys + (sb));  Y1 = *(const f32x4*)(ys + (sb) + 4); \
      Z0 = *(const f32x4*)(zs + (sb));  Z1 = *(const f32x4*)(zs + (sb) + 4); \
      W0 = *(const f32x4*)(nw + (sb));  W1 = *(const f32x4*)(nw + (sb) + 4); \
    } while (0)

#define PAIR_Q(PX, PY, PZ, PW, sidx)                                      \
    do {                                                                  \
      _Pragma("unroll")                                                   \
      for (int q = 0; q < 4; ++q) {                                       \
        f32x2 ax2 = {qx[q], qx[q]}, ay2 = {qy[q], qy[q]};                 \
        f32x2 az2 = {qz[q], qz[q]}, n12 = {n1[q], n1[q]};                 \
        f32x2 d = __builtin_elementwise_fma(az2, PZ, PW);                 \
        d = __builtin_elementwise_fma(ay2, PY, d);                        \
        d = __builtin_elementwise_fma(ax2, PX, d);                        \
        d = __builtin_elementwise_fma(m2, d, n12);                        \
        d = __builtin_elementwise_max(d, z2);                             \
        u32 k0 = (__float_as_uint(d[0]) & 0xFFFFFF00u) | (u32)(sidx);     \
        u32 k1 = (__float_as_uint(d[1]) & 0xFFFFFF00u) | (u32)((sidx) + 1); \
        INS3M(K[q][0][0], K[q][0][1], K[q][0][2], k0);                    \
        INS3M(K[q][1][0], K[q][1][1], K[q][1][2], k1);                    \
      }                                                                   \
    } while (0)

#define COMPUTE8(X0, X1, Y0, Y1, Z0, Z1, W0, W1, base)                    \
    do {                                                                  \
      PAIR_Q(SHL(X0), SHL(Y0), SHL(Z0), SHL(W0), (base));                 \
      PAIR_Q(SHH(X0), SHH(Y0), SHH(Z0), SHH(W0), (base) + 2);             \
      PAIR_Q(SHL(X1), SHL(Y1), SHL(Z1), SHL(W1), (base) + 4);             \
      PAIR_Q(SHH(X1), SHH(Y1), SHH(Z1), SHH(W1), (base) + 6);             \
    } while (0)

    f32x4 AX0, AX1, AY0, AY1, AZ0, AZ1, AW0, AW1;
    f32x4 BX0, BX1, BY0, BY1, BZ0, BZ1, BW0, BW1;
    LOAD8(AX0, AX1, AY0, AY1, AZ0, AZ1, AW0, AW1, 0);
#pragma unroll 1
    for (int s8 = 0; s8 < CHS_; s8 += 16) {
      LOAD8(BX0, BX1, BY0, BY1, BZ0, BZ1, BW0, BW1, s8 + 8);
      COMPUTE8(AX0, AX1, AY0, AY1, AZ0, AZ1, AW0, AW1, s8);
      LOAD8(AX0, AX1, AY0, AY1, AZ0, AZ1, AW0, AW1, s8 + 16);  // last iter reads pad
      COMPUTE8(BX0, BX1, BY0, BY1, BZ0, BZ1, BW0, BW1, s8 + 8);
    }

#pragma unroll
    for (int q = 0; q < 4; ++q) {
      INS3M(K[q][0][0], K[q][0][1], K[q][0][2], K[q][1][0]);
      INS3M(K[q][0][0], K[q][0][1], K[q][0][2], K[q][1][1]);
      INS3M(K[q][0][0], K[q][0][1], K[q][0][2], K[q][1][2]);
      u16* co = cand + ((size_t)(b * NCHUNK_ + chunk) * N_ + (nA + q * 256)) * 4;
      *(ushort4*)co = make_ushort4((u16)((K[q][0][0] & 0xFFu) + s0),
                                   (u16)((K[q][0][1] & 0xFFu) + s0),
                                   (u16)((K[q][0][2] & 0xFFu) + s0), 0);
    }
    return;
  }

  int tr = tid >> 4;
  int tc4 = (tid & 15) * 4;
  if (id < 1024) {
    int id2 = id - 512;
    int sx = id2 & 63, sy = (id2 >> 6) & 3, b = id2 >> 8;
    transpose_body(points2, p2t, 256, S_, 256, b, sx * 64, sy * 64, smem, tr, tc4);
    return;
  }
  int t = (id - 1024) * 256 + tid;
  int stride = 64 * 256;
  for (int i = t; i < 128 * KP_; i += stride) {
    int m = i / KP_, k = i - m * KP_;
    Wf[i] = (k < CIN_) ? f2b(fW[m * CIN_ + k]) : (u16)0;
  }
  for (int i = t; i < 128 * 128; i += stride) {
    W1o[i] = f2b(e1W[i]);
    W2o[i] = f2b(e2W[i]);
    W3o[i] = f2b(p1W[i]);
  }
  for (int i = t; i < 16 * 128; i += stride) {
    int m = i >> 7;
    Wp2[i] = (m < OC_) ? f2b(p2W[i]) : (u16)0;
  }
  for (int i = t; i < 5 * 128; i += stride) {
    int sg = i >> 7, c = i & 127;
    const float* bn; const float* bc; int Cc = 128;
    switch (sg) {
      case 0: bn = fbn;  bc = fb;  break;
      case 1: bn = e1bn; bc = e1b; break;
      case 2: bn = e2bn; bc = e2b; break;
      case 3: bn = p1bn; bc = p1b; break;
      default: bn = p2bn; bc = p2b; Cc = OC_; break;
    }
    float s = 0.f, tt = 0.f;
    if (c < Cc) {
      float g  = bn[0 * Cc + c], be = bn[1 * Cc + c];
      float mu = bn[2 * Cc + c], vv = bn[3 * Cc + c];
      float inv = 1.0f / sqrtf(vv + 1e-5f);
      s = g * inv;
      tt = (bc[c] - mu) * s + be;
    }
    st[sg * 256 + c] = s;
    st[sg * 256 + 128 + c] = tt;
  }
}

// ---------------------------------------------------------------------------
// f64 lexicographic (d, idx) top-3 insert -- matches stable top_k semantics
// ---------------------------------------------------------------------------
__device__ __forceinline__ void ins3(double d, int i,
                                     double& D0, double& D1, double& D2,
                                     int& I0, int& I1, int& I2) {
  if ((d < D2) || (d == D2 && i < I2)) {
    if ((d < D1) || (d == D1 && i < I1)) {
      D2 = D1; I2 = I1;
      if ((d < D0) || (d == D0 && i < I0)) { D1 = D0; I1 = I0; D0 = d; I0 = i; }
      else                                  { D1 = d; I1 = i; }
    } else { D2 = d; I2 = i; }
  }
}

// ---------------------------------------------------------------------------
// interp_kernel: gather/bandwidth phase. Round-6: cand is chunk-major
// ushort4-padded; part p reads chunks {2p, 2p+1} -- same 6 candidates in the
// same insertion order as the old [query][48] layout.
// ---------------------------------------------------------------------------
__global__ __launch_bounds__(256) void interp_kernel(
    const float* __restrict__ xyz1, const float* __restrict__ xyz2,
    const u16* __restrict__ cand, const u16* __restrict__ p2t,
    const float* __restrict__ last_pred, u16* __restrict__ xq) {
  __shared__ int   iS[32][3];
  __shared__ float wS[32][3];
  int id = blockIdx.x;
  int b = id >> 9;
  int n0 = (id & 511) * 32;
  int tid = threadIdx.x;

  // ---- phase 1: refine ----
  {
#pragma clang fp contract(off)
    int qi = tid >> 3, part = tid & 7;
    int nq = n0 + qi;
    int qg = b * N_ + nq;
    ushort4 ca = *(const ushort4*)(cand +
        ((size_t)(b * NCHUNK_ + 2 * part) * N_ + nq) * 4);
    ushort4 cbv = *(const ushort4*)(cand +
        ((size_t)(b * NCHUNK_ + 2 * part + 1) * N_ + nq) * 4);
    int ii[6] = {ca.x, ca.y, ca.z, cbv.x, cbv.y, cbv.z};
    const float* x2b = xyz2 + (size_t)b * S_ * 3;
    float pcx[6], pcy[6], pcz[6];
#pragma unroll
    for (int j = 0; j < 6; ++j) {
      const float* p = x2b + (size_t)ii[j] * 3;
      pcx[j] = p[0]; pcy[j] = p[1]; pcz[j] = p[2];
    }
    const float* x1 = xyz1 + (size_t)qg * 3;
    double ax = x1[0], ay = x1[1], az = x1[2];
    double n1 = (ax * ax + ay * ay) + az * az;
    double D0 = 1e300, D1 = 1e300, D2v = 1e300;
    int I0 = 2147483647, I1 = 2147483647, I2 = 2147483647;
#pragma unroll
    for (int j = 0; j < 6; ++j) {
      double px = pcx[j], py = pcy[j], pz = pcz[j];
      double n2 = (px * px + py * py) + pz * pz;
      double dot = (ax * px + ay * py) + az * pz;
      double d = (n1 + n2) - 2.0 * dot;
      ins3(d, ii[j], D0, D1, D2v, I0, I1, I2);
    }
#pragma unroll
    for (int r = 0; r < 3; ++r) {
      int m = 1 << r;
      double e0 = __shfl_xor(D0, m);
      double e1 = __shfl_xor(D1, m);
      double e2 = __shfl_xor(D2v, m);
      int j0 = __shfl_xor(I0, m);
      int j1 = __shfl_xor(I1, m);
      int j2 = __shfl_xor(I2, m);
      ins3(e0, j0, D0, D1, D2v, I0, I1, I2);
      ins3(e1, j1, D0, D1, D2v, I0, I1, I2);
      ins3(e2, j2, D0, D1, D2v, I0, I1, I2);
    }
    if (part == 0) {
      double r0 = 1.0 / (D0 + 1e-8);
      double r1 = 1.0 / (D1 + 1e-8);
      double r2 = 1.0 / (D2v + 1e-8);
      double sum = (r0 + r1) + r2;
      wS[qi][0] = (float)(r0 / sum);
      wS[qi][1] = (float)(r1 / sum);
      wS[qi][2] = (float)(r2 / sum);
      iS[qi][0] = I0; iS[qi][1] = I1; iS[qi][2] = I2;
    }
  }
  __syncthreads();

  // ---- phase 2: interp, one (query, 32-channel group) per lane ----
  int wv = tid >> 6, lane = tid & 63;
  int q = wv * 8 + (lane >> 3);    // local query 0..31
  int cg = lane & 7;               // channel group: ch [cg*32, cg*32+32)
  int n = n0 + q;
  int i0 = iS[q][0], i1 = iS[q][1], i2 = iS[q][2];
  float w0 = wS[q][0], w1 = wS[q][1], w2 = wS[q][2];
  const u16* p2b = p2t + (size_t)b * S_ * D2_;
  const u16* r0p = p2b + (size_t)i0 * D2_ + cg * 32;
  const u16* r1p = p2b + (size_t)i1 * D2_ + cg * 32;
  const u16* r2p = p2b + (size_t)i2 * D2_ + cg * 32;
  u16* xrow = xq + (size_t)(b * N_ + n) * XQ_P;
#pragma unroll
  for (int j = 0; j < 8; ++j) {
    ushort4 a = *(const ushort4*)(r0p + j * 4);
    ushort4 e = *(const ushort4*)(r1p + j * 4);
    ushort4 c = *(const ushort4*)(r2p + j * 4);
    ushort4 v;
    v.x = f2b((w0 * b2f(a.x) + w1 * b2f(e.x)) + w2 * b2f(c.x));
    v.y = f2b((w0 * b2f(a.y) + w1 * b2f(e.y)) + w2 * b2f(c.y));
    v.z = f2b((w0 * b2f(a.z) + w1 * b2f(e.z)) + w2 * b2f(c.z));
    v.w = f2b((w0 * b2f(a.w) + w1 * b2f(e.w)) + w2 * b2f(c.w));
    *(ushort4*)(xrow + cg * 32 + j * 4) = v;
  }
  if (cg == 0) {
    const float* lpb = last_pred + (size_t)b * S_ * OC_;
    u16 pv[16];
#pragma unroll
    for (int c = 0; c < 16; ++c) pv[c] = 0;
#pragma unroll
    for (int c = 0; c < OC_; ++c) {
      float l0 = lpb[(size_t)i0 * OC_ + c];
      float l1 = lpb[(size_t)i1 * OC_ + c];
      float l2 = lpb[(size_t)i2 * OC_ + c];
      pv[c] = f2b((w0 * l0 + w1 * l1) + w2 * l2);
    }
#pragma unroll
    for (int c4 = 0; c4 < 4; ++c4) {
      *(ushort4*)(xrow + 256 + c4 * 4) =
          make_ushort4(pv[c4 * 4], pv[c4 * 4 + 1], pv[c4 * 4 + 2], pv[c4 * 4 + 3]);
    }
  }
}

// ---------------------------------------------------------------------------
// gemm_kernel: pure compute phase (unchanged from round 5).
// ---------------------------------------------------------------------------
__device__ __forceinline__ void gemm32(const u16* __restrict__ W, const u16* xb,
                                       int l15, int lq, int wv, f32x4 acc[2][2]) {
#pragma unroll
  for (int mtl = 0; mtl < 2; ++mtl) {
    acc[mtl][0] = (f32x4){0.f, 0.f, 0.f, 0.f};
    acc[mtl][1] = (f32x4){0.f, 0.f, 0.f, 0.f};
  }
#pragma unroll
  for (int ks = 0; ks < 4; ++ks) {
    int ko = ks * 32 + lq * 8;
    s16x8 b0 = *(const s16x8*)(xb + l15 * 136 + ko);
    s16x8 b1 = *(const s16x8*)(xb + (16 + l15) * 136 + ko);
#pragma unroll
    for (int mtl = 0; mtl < 2; ++mtl) {
      s16x8 a = *(const s16x8*)(W + (size_t)((wv * 2 + mtl) * 16 + l15) * 128 + ko);
      acc[mtl][0] = MFMA16(a, b0, acc[mtl][0]);
      acc[mtl][1] = MFMA16(a, b1, acc[mtl][1]);
    }
  }
}

__global__ __launch_bounds__(256, 4) void gemm_kernel(
    const float* __restrict__ points1, const u16* __restrict__ xq,
    const u16* __restrict__ Wf,
    const u16* __restrict__ W1, const u16* __restrict__ W2,
    const u16* __restrict__ W3, const u16* __restrict__ Wp2,
    const float* __restrict__ st, float* __restrict__ out) {
  __shared__ __align__(16) u16 xb0[32 * 136];
  __shared__ __align__(16) u16 xb1[32 * 136];
  int b = blockIdx.y;
  int n0 = blockIdx.x * 32;
  int tid = threadIdx.x;
  int wv = tid >> 6, lane = tid & 63;
  int l15 = lane & 15, lq = lane >> 4;
  f32x4 acc[2][2];

  // ---- stage 0: stage points1 tile [c=128][n=32] -> xb1[n][c] bf16 ----
  {
    int n4 = (tid & 7) * 4;
    int cb = tid >> 3;             // 0..31
    const float* p1b = points1 + (size_t)b * C_ * N_;
#pragma unroll
    for (int rep = 0; rep < 4; ++rep) {
      int c = cb + rep * 32;
      float4 v = *(const float4*)(p1b + (size_t)c * N_ + n0 + n4);
      xb1[(n4 + 0) * 136 + c] = f2b(v.x);
      xb1[(n4 + 1) * 136 + c] = f2b(v.y);
      xb1[(n4 + 2) * 136 + c] = f2b(v.z);
      xb1[(n4 + 3) * 136 + c] = f2b(v.w);
    }
  }
  __syncthreads();

  // ---- stage 1: fuse (K=416): k<128 from xb1 (staged points1), rest xq ----
#pragma unroll
  for (int mtl = 0; mtl < 2; ++mtl) {
    acc[mtl][0] = (f32x4){0.f, 0.f, 0.f, 0.f};
    acc[mtl][1] = (f32x4){0.f, 0.f, 0.f, 0.f};
  }
  {
#pragma unroll 2
    for (int ks = 0; ks < 4; ++ks) {
      int ko = ks * 32 + lq * 8;
      s16x8 bf0 = *(const s16x8*)(&xb1[l15 * 136 + ko]);
      s16x8 bf1 = *(const s16x8*)(&xb1[(16 + l15) * 136 + ko]);
#pragma unroll
      for (int mtl = 0; mtl < 2; ++mtl) {
        s16x8 a = *(const s16x8*)(Wf + (size_t)((wv * 2 + mtl) * 16 + l15) * KP_ + ko);
        acc[mtl][0] = MFMA16(a, bf0, acc[mtl][0]);
        acc[mtl][1] = MFMA16(a, bf1, acc[mtl][1]);
      }
    }
    const u16* qrow0 = xq + ((size_t)(b * N_ + n0 + l15)) * XQ_P;
    const u16* qrow1 = qrow0 + (size_t)16 * XQ_P;
#pragma unroll 3
    for (int ks = 0; ks < 9; ++ks) {
      int col = ks * 32 + lq * 8;
      s16x8 bf0 = {0, 0, 0, 0, 0, 0, 0, 0};
      s16x8 bf1 = {0, 0, 0, 0, 0, 0, 0, 0};
      if (ks < 8 || lq < 2) {     // cols >= 272 are implicit zeros (W also 0)
        bf0 = *(const s16x8*)(qrow0 + col);
        bf1 = *(const s16x8*)(qrow1 + col);
      }
#pragma unroll
      for (int mtl = 0; mtl < 2; ++mtl) {
        s16x8 a = *(const s16x8*)(Wf + (size_t)((wv * 2 + mtl) * 16 + l15) * KP_ + 128 + col);
        acc[mtl][0] = MFMA16(a, bf0, acc[mtl][0]);
        acc[mtl][1] = MFMA16(a, bf1, acc[mtl][1]);
      }
    }
  }
  __syncthreads();   // xb1 reads done (stage 2 will overwrite it)
#pragma unroll
  for (int mtl = 0; mtl < 2; ++mtl) {
    int m4 = (wv * 2 + mtl) * 16 + lq * 4;
    f32x4 sc = *(const f32x4*)(st + 0 * 256 + m4);
    f32x4 bi = *(const f32x4*)(st + 0 * 256 + 128 + m4);
#pragma unroll
    for (int nt = 0; nt < 2; ++nt) {
      int n_l = nt * 16 + l15;
      ushort4 v;
      v.x = f2b(fmaxf(acc[mtl][nt][0] * sc[0] + bi[0], 0.f));
      v.y = f2b(fmaxf(acc[mtl][nt][1] * sc[1] + bi[1], 0.f));
      v.z = f2b(fmaxf(acc[mtl][nt][2] * sc[2] + bi[2], 0.f));
      v.w = f2b(fmaxf(acc[mtl][nt][3] * sc[3] + bi[3], 0.f));
      *(ushort4*)(&xb0[n_l * 136 + m4]) = v;
    }
  }
  __syncthreads();

  // ---- stage 2: ext1 (K=128), xb0 -> xb1 ----
  gemm32(W1, xb0, l15, lq, wv, acc);
#pragma unroll
  for (int mtl = 0; mtl < 2; ++mtl) {
    int m4 = (wv * 2 + mtl) * 16 + lq * 4;
    f32x4 sc = *(const f32x4*)(st + 1 * 256 + m4);
    f32x4 bi = *(const f32x4*)(st + 1 * 256 + 128 + m4);
#pragma unroll
    for (int nt = 0; nt < 2; ++nt) {
      int n_l = nt * 16 + l15;
      ushort4 v;
      v.x = f2b(fmaxf(acc[mtl][nt][0] * sc[0] + bi[0], 0.f));
      v.y = f2b(fmaxf(acc[mtl][nt][1] * sc[1] + bi[1], 0.f));
      v.z = f2b(fmaxf(acc[mtl][nt][2] * sc[2] + bi[2], 0.f));
      v.w = f2b(fmaxf(acc[mtl][nt][3] * sc[3] + bi[3], 0.f));
      *(ushort4*)(&xb1[n_l * 136 + m4]) = v;
    }
  }
  __syncthreads();

  // ---- stage 3: ext2 (K=128), xb1 -> xb0, + residual(xb0), store out0 ----
  gemm32(W2, xb1, l15, lq, wv, acc);
#pragma unroll
  for (int mtl = 0; mtl < 2; ++mtl) {
    int m4 = (wv * 2 + mtl) * 16 + lq * 4;
    f32x4 sc = *(const f32x4*)(st + 2 * 256 + m4);
    f32x4 bi = *(const f32x4*)(st + 2 * 256 + 128 + m4);
#pragma unroll
    for (int nt = 0; nt < 2; ++nt) {
      int n_l = nt * 16 + l15;
      int n_g = n0 + n_l;
      ushort4 xp = *(const ushort4*)(&xb0[n_l * 136 + m4]);
      float v0 = fmaxf(acc[mtl][nt][0] * sc[0] + bi[0] + b2f(xp.x), 0.f);
      float v1 = fmaxf(acc[mtl][nt][1] * sc[1] + bi[1] + b2f(xp.y), 0.f);
      float v2 = fmaxf(acc[mtl][nt][2] * sc[2] + bi[2] + b2f(xp.z), 0.f);
      float v3 = fmaxf(acc[mtl][nt][3] * sc[3] + bi[3] + b2f(xp.w), 0.f);
      ushort4 v;
      v.x = f2b(v0); v.y = f2b(v1); v.z = f2b(v2); v.w = f2b(v3);
      *(ushort4*)(&xb0[n_l * 136 + m4]) = v;
      out[((size_t)(b * C_ + m4 + 0)) * N_ + n_g] = v0;
      out[((size_t)(b * C_ + m4 + 1)) * N_ + n_g] = v1;
      out[((size_t)(b * C_ + m4 + 2)) * N_ + n_g] = v2;
      out[((size_t)(b * C_ + m4 + 3)) * N_ + n_g] = v3;
    }
  }
  __syncthreads();

  // ---- stage 4: pred1 (K=128), xb0 -> xb1, store out1 ([B][N][128]) ----
  gemm32(W3, xb0, l15, lq, wv, acc);
  {
    float* out1 = out + (size_t)B_ * C_ * N_;
#pragma unroll
    for (int mtl = 0; mtl < 2; ++mtl) {
      int m4 = (wv * 2 + mtl) * 16 + lq * 4;
      f32x4 sc = *(const f32x4*)(st + 3 * 256 + m4);
      f32x4 bi = *(const f32x4*)(st + 3 * 256 + 128 + m4);
#pragma unroll
      for (int nt = 0; nt < 2; ++nt) {
        int n_l = nt * 16 + l15;
        int n_g = n0 + n_l;
        float v0 = fmaxf(acc[mtl][nt][0] * sc[0] + bi[0], 0.f);
        float v1 = fmaxf(acc[mtl][nt][1] * sc[1] + bi[1], 0.f);
        float v2 = fmaxf(acc[mtl][nt][2] * sc[2] + bi[2], 0.f);
        float v3 = fmaxf(acc[mtl][nt][3] * sc[3] + bi[3], 0.f);
        ushort4 v;
        v.x = f2b(v0); v.y = f2b(v1); v.z = f2b(v2); v.w = f2b(v3);
        *(ushort4*)(&xb1[n_l * 136 + m4]) = v;
        float4 o4 = make_float4(v0, v1, v2, v3);
        *(float4*)(out1 + ((size_t)(b * N_ + n_g)) * 128 + m4) = o4;
      }
    }
  }
  __syncthreads();

  // ---- stage 5: pred2 (M=13 pad 16, K=128): waves 0,1 each do one nt ----
  if (wv < 2) {
    f32x4 a2 = (f32x4){0.f, 0.f, 0.f, 0.f};
#pragma unroll
    for (int ks = 0; ks < 4; ++ks) {
      int ko = ks * 32 + lq * 8;
      s16x8 b0 = *(const s16x8*)(&xb1[(wv * 16 + l15) * 136 + ko]);
      s16x8 a = *(const s16x8*)(Wp2 + (size_t)l15 * 128 + ko);
      a2 = MFMA16(a, b0, a2);
    }
    float* out2 = out + (size_t)B_ * C_ * N_ + (size_t)B_ * N_ * 128;
    f32x4 sc = *(const f32x4*)(st + 4 * 256 + lq * 4);
    f32x4 bi = *(const f32x4*)(st + 4 * 256 + 128 + lq * 4);
    int n_g = n0 + wv * 16 + l15;
#pragma unroll
    for (int r = 0; r < 4; ++r) {
      int m = lq * 4 + r;
      if (m < OC_) {
        out2[((size_t)(b * N_ + n_g)) * OC_ + m] =
            fmaxf(a2[r] * sc[r] + bi[r], 0.f);
      }
    }
  }
}

// ---------------------------------------------------------------------------
extern "C" void kernel_launch(void* const* d_in, const int* in_sizes, int n_in,
                              void* d_out, int out_size, void* d_ws, size_t ws_size,
                              hipStream_t stream) {
  const float* xyz1      = (const float*)d_in[0];
  const float* xyz2      = (const float*)d_in[1];
  const float* points1   = (const float*)d_in[2];
  const float* points2   = (const float*)d_in[3];
  const float* last_pred = (const float*)d_in[4];
  const float* fuse_W    = (const float*)d_in[5];
  const float* fuse_b    = (const float*)d_in[6];
  const float* fuse_bn   = (const float*)d_in[7];
  const float* ext1_W    = (const float*)d_in[8];
  const float* ext1_b    = (const float*)d_in[9];
  const float* ext1_bn   = (const float*)d_in[10];
  const float* ext2_W    = (const float*)d_in[11];
  const float* ext2_b    = (const float*)d_in[12];
  const float* ext2_bn   = (const float*)d_in[13];
  const float* pred1_W   = (const float*)d_in[14];
  const float* pred1_b   = (const float*)d_in[15];
  const float* pred1_bn  = (const float*)d_in[16];
  const float* pred2_W   = (const float*)d_in[17];
  const float* pred2_b   = (const float*)d_in[18];
  const float* pred2_bn  = (const float*)d_in[19];

  char* ws = (char*)d_ws;
  u16*   p2t  = (u16*)(ws + 0);                // 2*4096*256*2    =  4,194,304
  u16*   cand = (u16*)(ws + 4194304);          // 2*16*16384*4*2  =  4,194,304
  u16*   Wf   = (u16*)(ws + 8388608);          // 128*416*2       =    106,496
  u16*   W1   = (u16*)(ws + 8495104);          // 128*128*2       =     32,768
  u16*   W2   = (u16*)(ws + 8527872);          //                       32,768
  u16*   W3   = (u16*)(ws + 8560640);          //                       32,768
  u16*   Wp2  = (u16*)(ws + 8593408);          // 16*128*2        =      4,096
  float* st   = (float*)(ws + 8597504);        // 5*256*4         =      5,120
  u16*   xq   = (u16*)(ws + 8602624);          // 2*16384*272*2   = 17,825,792
                                               // total 26,428,416 B

  setup_scan_kernel<<<dim3(1088), dim3(256), 0, stream>>>(
      xyz1, xyz2, points2,
      fuse_W, fuse_b, fuse_bn, ext1_W, ext1_b, ext1_bn, ext2_W, ext2_b, ext2_bn,
      pred1_W, pred1_b, pred1_bn, pred2_W, pred2_b, pred2_bn,
      cand, p2t, Wf, W1, W2, W3, Wp2, st);

  interp_kernel<<<dim3(1024), dim3(256), 0, stream>>>(
      xyz1, xyz2, cand, p2t, last_pred, xq);

  gemm_kernel<<<dim3(N_ / 32, B_), dim3(256), 0, stream>>>(
      points1, xq, Wf, W1, W2, W3, Wp2, st, (float*)d_out);
}

// Round 7
// 216.989 us; speedup vs baseline: 1.0191x; 1.0087x over previous
//
#include <hip/hip_runtime.h>
#include <stdint.h>

#define B_   2
#define N_   16384
#define S_   4096
#define D2_  256
#define CIN_ 397
#define KP_  416      // Cin padded to 13*32 for MFMA K-slabs
#define C_   128
#define OC_  13
#define NCHUNK_ 16
#define CHS_ (S_ / NCHUNK_)       // 256 points per scan chunk
#define XQ_P 272                  // xq pitch in u16 (269 used, 16B-mult)

typedef unsigned short u16;
typedef unsigned int u32;
typedef short s16x8 __attribute__((ext_vector_type(8)));
typedef float f32x4 __attribute__((ext_vector_type(4)));
typedef float f32x2 __attribute__((ext_vector_type(2)));

#define MFMA16(a, b, c) __builtin_amdgcn_mfma_f32_16x16x32_bf16((a), (b), (c), 0, 0, 0)

__device__ __forceinline__ float b2f(u16 h) {
  union { unsigned int u; float f; } v; v.u = ((unsigned int)h) << 16; return v.f;
}
__device__ __forceinline__ u16 f2b(float f) {
  union { float f; unsigned int u; } v; v.f = f;
  unsigned int r = v.u + 0x7fffu + ((v.u >> 16) & 1u);
  return (u16)(r >> 16);
}

// 3-op branchless sorted-top3 insert on u32 keys (exact-equivalent to 5-op
// min/max version; v_med3_u32 has no builtin -> inline asm).
#define INS3M(k0, k1, k2, key)                                            \
  do {                                                                    \
    u32 _m1, _m2;                                                         \
    asm("v_med3_u32 %0, %1, %2, %3" : "=v"(_m1) : "v"(k0), "v"(k1), "v"(key)); \
    asm("v_med3_u32 %0, %1, %2, %3" : "=v"(_m2) : "v"(k1), "v"(k2), "v"(key)); \
    k0 = min(k0, key);                                                    \
    k1 = _m1;                                                             \
    k2 = _m2;                                                             \
  } while (0)

#define SHL(v) __builtin_shufflevector((v), (v), 0, 1)
#define SHH(v) __builtin_shufflevector((v), (v), 2, 3)

// ---------------------------------------------------------------------------
// setup_scan: ONE launch, 1600 blocks.
// [0,1024): knn scan, 2 queries/thread + register double-buffered point
//   blocks. Round-7: R6 showed 512 scan blocks = 2 waves/SIMD co-resident
//   with per-wave issue duty only ~28% -- combining the fixed inner loop
//   (reg-dbuf, R6) with 2x blocks (Q=2, R5) doubles resident waves/SIMD.
// [1024,1536): transpose points2 -> p2t. [1536,1600): weight/bn prep.
// ---------------------------------------------------------------------------
__device__ __forceinline__ void transpose_body(
    const float* __restrict__ in, u16* __restrict__ out,
    int C, int S, int opitch, int b, int s0, int c0,
    float* __restrict__ tile, int tr, int tc4) {
  const float* ip = in + (size_t)b * C * S;
  u16* op = out + (size_t)b * S * opitch;
#pragma unroll
  for (int r = 0; r < 64; r += 16) {
    float4 v = *(const float4*)(ip + (size_t)(c0 + tr + r) * S + s0 + tc4);
    tile[(tr + r) * 65 + tc4 + 0] = v.x;
    tile[(tr + r) * 65 + tc4 + 1] = v.y;
    tile[(tr + r) * 65 + tc4 + 2] = v.z;
    tile[(tr + r) * 65 + tc4 + 3] = v.w;
  }
  __syncthreads();
#pragma unroll
  for (int r = 0; r < 64; r += 16) {
    ushort4 v;
    v.x = f2b(tile[(tc4 + 0) * 65 + tr + r]);
    v.y = f2b(tile[(tc4 + 1) * 65 + tr + r]);
    v.z = f2b(tile[(tc4 + 2) * 65 + tr + r]);
    v.w = f2b(tile[(tc4 + 3) * 65 + tr + r]);
    *(ushort4*)(op + (size_t)(s0 + tr + r) * opitch + c0 + tc4) = v;
  }
}

__global__ __launch_bounds__(256) void setup_scan_kernel(
    const float* __restrict__ xyz1, const float* __restrict__ xyz2,
    const float* __restrict__ points2,
    const float* __restrict__ fW, const float* __restrict__ fb,
    const float* __restrict__ fbn,
    const float* __restrict__ e1W, const float* __restrict__ e1b,
    const float* __restrict__ e1bn,
    const float* __restrict__ e2W, const float* __restrict__ e2b,
    const float* __restrict__ e2bn,
    const float* __restrict__ p1W, const float* __restrict__ p1b,
    const float* __restrict__ p1bn,
    const float* __restrict__ p2W, const float* __restrict__ p2b,
    const float* __restrict__ p2bn,
    u16* __restrict__ cand, u16* __restrict__ p2t,
    u16* __restrict__ Wf, u16* __restrict__ W1o,
    u16* __restrict__ W2o, u16* __restrict__ W3o,
    u16* __restrict__ Wp2, float* __restrict__ st) {
  __shared__ __align__(16) float smem[64 * 65];
  int id = blockIdx.x;
  int tid = threadIdx.x;

  if (id < 1024) {
    // ---- knn scan: SoA LDS (272-spaced, 8-float pad for prefetch
    //      overrun); 2 queries/thread; d = fma(-2, dot', n1) ----
    float* xs = smem;
    float* ys = smem + 272;
    float* zs = smem + 544;
    float* nw = smem + 816;
    int chunk = id & 15;
    int ny = (id >> 4) & 31;
    int b = id >> 9;
    int s0 = chunk * CHS_;
    const float* x2 = xyz2 + ((size_t)b * S_ + s0) * 3;
    {
      float xx = x2[tid * 3], yy = x2[tid * 3 + 1], zz = x2[tid * 3 + 2];
      xs[tid] = xx; ys[tid] = yy; zs[tid] = zz;
      nw[tid] = -0.5f * fmaf(xx, xx, fmaf(yy, yy, zz * zz));
    }
    __syncthreads();
    int nA = ny * 512 + tid;     // queries nA + {0,256}
    float qx[2], qy[2], qz[2], n1[2];
#pragma unroll
    for (int q = 0; q < 2; ++q) {
      const float* x1 = xyz1 + ((size_t)b * N_ + nA + q * 256) * 3;
      qx[q] = x1[0]; qy[q] = x1[1]; qz[q] = x1[2];
      n1[q] = fmaf(qx[q], qx[q], fmaf(qy[q], qy[q], qz[q] * qz[q]));
    }
    u32 K[2][2][3];
#pragma unroll
    for (int q = 0; q < 2; ++q)
#pragma unroll
      for (int e = 0; e < 2; ++e)
#pragma unroll
        for (int r = 0; r < 3; ++r) K[q][e][r] = ~0u;
    f32x2 m2 = {-2.f, -2.f}, z2 = {0.f, 0.f};

#define LOAD8(X0, X1, Y0, Y1, Z0, Z1, W0, W1, sb)                         \
    do {                                                                  \
      X0 = *(const f32x4*)(xs + (sb));  X1 = *(const f32x4*)(xs + (sb) + 4); \
      Y0 = *(const f32x4*)(ys + (sb));  Y1 = *(const f32x4*)(ys + (sb) + 4); \
      Z0 = *(const f32x4*)(zs + (sb));  Z1 = *(const f32x4*)(zs + (sb) + 4); \
      W0 = *(const f32x4*)(nw + (sb));  W1 = *(const f32x4*)(nw + (sb) + 4); \
    } while (0)

#define PAIR_Q(PX, PY, PZ, PW, sidx)                                      \
    do {                                                                  \
      _Pragma("unroll")                                                   \
      for (int q = 0; q < 2; ++q) {                                       \
        f32x2 ax2 = {qx[q], qx[q]}, ay2 = {qy[q], qy[q]};                 \
        f32x2 az2 = {qz[q], qz[q]}, n12 = {n1[q], n1[q]};                 \
        f32x2 d = __builtin_elementwise_fma(az2, PZ, PW);                 \
        d = __builtin_elementwise_fma(ay2, PY, d);                        \
        d = __builtin_elementwise_fma(ax2, PX, d);                        \
        d = __builtin_elementwise_fma(m2, d, n12);                        \
        d = __builtin_elementwise_max(d, z2);                             \
        u32 k0 = (__float_as_uint(d[0]) & 0xFFFFFF00u) | (u32)(sidx);     \
        u32 k1 = (__float_as_uint(d[1]) & 0xFFFFFF00u) | (u32)((sidx) + 1); \
        INS3M(K[q][0][0], K[q][0][1], K[q][0][2], k0);                    \
        INS3M(K[q][1][0], K[q][1][1], K[q][1][2], k1);                    \
      }                                                                   \
    } while (0)

#define COMPUTE8(X0, X1, Y0, Y1, Z0, Z1, W0, W1, base)                    \
    do {                                                                  \
      PAIR_Q(SHL(X0), SHL(Y0), SHL(Z0), SHL(W0), (base));                 \
      PAIR_Q(SHH(X0), SHH(Y0), SHH(Z0), SHH(W0), (base) + 2);             \
      PAIR_Q(SHL(X1), SHL(Y1), SHL(Z1), SHL(W1), (base) + 4);             \
      PAIR_Q(SHH(X1), SHH(Y1), SHH(Z1), SHH(W1), (base) + 6);             \
    } while (0)

    f32x4 AX0, AX1, AY0, AY1, AZ0, AZ1, AW0, AW1;
    f32x4 BX0, BX1, BY0, BY1, BZ0, BZ1, BW0, BW1;
    LOAD8(AX0, AX1, AY0, AY1, AZ0, AZ1, AW0, AW1, 0);
#pragma unroll 1
    for (int s8 = 0; s8 < CHS_; s8 += 16) {
      LOAD8(BX0, BX1, BY0, BY1, BZ0, BZ1, BW0, BW1, s8 + 8);
      COMPUTE8(AX0, AX1, AY0, AY1, AZ0, AZ1, AW0, AW1, s8);
      LOAD8(AX0, AX1, AY0, AY1, AZ0, AZ1, AW0, AW1, s8 + 16);  // last iter reads pad
      COMPUTE8(BX0, BX1, BY0, BY1, BZ0, BZ1, BW0, BW1, s8 + 8);
    }

#pragma unroll
    for (int q = 0; q < 2; ++q) {
      INS3M(K[q][0][0], K[q][0][1], K[q][0][2], K[q][1][0]);
      INS3M(K[q][0][0], K[q][0][1], K[q][0][2], K[q][1][1]);
      INS3M(K[q][0][0], K[q][0][1], K[q][0][2], K[q][1][2]);
      u16* co = cand + ((size_t)(b * NCHUNK_ + chunk) * N_ + (nA + q * 256)) * 4;
      *(ushort4*)co = make_ushort4((u16)((K[q][0][0] & 0xFFu) + s0),
                                   (u16)((K[q][0][1] & 0xFFu) + s0),
                                   (u16)((K[q][0][2] & 0xFFu) + s0), 0);
    }
    return;
  }

  int tr = tid >> 4;
  int tc4 = (tid & 15) * 4;
  if (id < 1536) {
    int id2 = id - 1024;
    int sx = id2 & 63, sy = (id2 >> 6) & 3, b = id2 >> 8;
    transpose_body(points2, p2t, 256, S_, 256, b, sx * 64, sy * 64, smem, tr, tc4);
    return;
  }
  int t = (id - 1536) * 256 + tid;
  int stride = 64 * 256;
  for (int i = t; i < 128 * KP_; i += stride) {
    int m = i / KP_, k = i - m * KP_;
    Wf[i] = (k < CIN_) ? f2b(fW[m * CIN_ + k]) : (u16)0;
  }
  for (int i = t; i < 128 * 128; i += stride) {
    W1o[i] = f2b(e1W[i]);
    W2o[i] = f2b(e2W[i]);
    W3o[i] = f2b(p1W[i]);
  }
  for (int i = t; i < 16 * 128; i += stride) {
    int m = i >> 7;
    Wp2[i] = (m < OC_) ? f2b(p2W[i]) : (u16)0;
  }
  for (int i = t; i < 5 * 128; i += stride) {
    int sg = i >> 7, c = i & 127;
    const float* bn; const float* bc; int Cc = 128;
    switch (sg) {
      case 0: bn = fbn;  bc = fb;  break;
      case 1: bn = e1bn; bc = e1b; break;
      case 2: bn = e2bn; bc = e2b; break;
      case 3: bn = p1bn; bc = p1b; break;
      default: bn = p2bn; bc = p2b; Cc = OC_; break;
    }
    float s = 0.f, tt = 0.f;
    if (c < Cc) {
      float g  = bn[0 * Cc + c], be = bn[1 * Cc + c];
      float mu = bn[2 * Cc + c], vv = bn[3 * Cc + c];
      float inv = 1.0f / sqrtf(vv + 1e-5f);
      s = g * inv;
      tt = (bc[c] - mu) * s + be;
    }
    st[sg * 256 + c] = s;
    st[sg * 256 + 128 + c] = tt;
  }
}

// ---------------------------------------------------------------------------
// f64 lexicographic (d, idx) top-3 insert -- matches stable top_k semantics
// ---------------------------------------------------------------------------
__device__ __forceinline__ void ins3(double d, int i,
                                     double& D0, double& D1, double& D2,
                                     int& I0, int& I1, int& I2) {
  if ((d < D2) || (d == D2 && i < I2)) {
    if ((d < D1) || (d == D1 && i < I1)) {
      D2 = D1; I2 = I1;
      if ((d < D0) || (d == D0 && i < I0)) { D1 = D0; I1 = I0; D0 = d; I0 = i; }
      else                                  { D1 = d; I1 = i; }
    } else { D2 = d; I2 = i; }
  }
}

// ---------------------------------------------------------------------------
// interp_kernel: gather/bandwidth phase (unchanged from round 6).
// ---------------------------------------------------------------------------
__global__ __launch_bounds__(256) void interp_kernel(
    const float* __restrict__ xyz1, const float* __restrict__ xyz2,
    const u16* __restrict__ cand, const u16* __restrict__ p2t,
    const float* __restrict__ last_pred, u16* __restrict__ xq) {
  __shared__ int   iS[32][3];
  __shared__ float wS[32][3];
  int id = blockIdx.x;
  int b = id >> 9;
  int n0 = (id & 511) * 32;
  int tid = threadIdx.x;

  // ---- phase 1: refine ----
  {
#pragma clang fp contract(off)
    int qi = tid >> 3, part = tid & 7;
    int nq = n0 + qi;
    int qg = b * N_ + nq;
    ushort4 ca = *(const ushort4*)(cand +
        ((size_t)(b * NCHUNK_ + 2 * part) * N_ + nq) * 4);
    ushort4 cbv = *(const ushort4*)(cand +
        ((size_t)(b * NCHUNK_ + 2 * part + 1) * N_ + nq) * 4);
    int ii[6] = {ca.x, ca.y, ca.z, cbv.x, cbv.y, cbv.z};
    const float* x2b = xyz2 + (size_t)b * S_ * 3;
    float pcx[6], pcy[6], pcz[6];
#pragma unroll
    for (int j = 0; j < 6; ++j) {
      const float* p = x2b + (size_t)ii[j] * 3;
      pcx[j] = p[0]; pcy[j] = p[1]; pcz[j] = p[2];
    }
    const float* x1 = xyz1 + (size_t)qg * 3;
    double ax = x1[0], ay = x1[1], az = x1[2];
    double n1 = (ax * ax + ay * ay) + az * az;
    double D0 = 1e300, D1 = 1e300, D2v = 1e300;
    int I0 = 2147483647, I1 = 2147483647, I2 = 2147483647;
#pragma unroll
    for (int j = 0; j < 6; ++j) {
      double px = pcx[j], py = pcy[j], pz = pcz[j];
      double n2 = (px * px + py * py) + pz * pz;
      double dot = (ax * px + ay * py) + az * pz;
      double d = (n1 + n2) - 2.0 * dot;
      ins3(d, ii[j], D0, D1, D2v, I0, I1, I2);
    }
#pragma unroll
    for (int r = 0; r < 3; ++r) {
      int m = 1 << r;
      double e0 = __shfl_xor(D0, m);
      double e1 = __shfl_xor(D1, m);
      double e2 = __shfl_xor(D2v, m);
      int j0 = __shfl_xor(I0, m);
      int j1 = __shfl_xor(I1, m);
      int j2 = __shfl_xor(I2, m);
      ins3(e0, j0, D0, D1, D2v, I0, I1, I2);
      ins3(e1, j1, D0, D1, D2v, I0, I1, I2);
      ins3(e2, j2, D0, D1, D2v, I0, I1, I2);
    }
    if (part == 0) {
      double r0 = 1.0 / (D0 + 1e-8);
      double r1 = 1.0 / (D1 + 1e-8);
      double r2 = 1.0 / (D2v + 1e-8);
      double sum = (r0 + r1) + r2;
      wS[qi][0] = (float)(r0 / sum);
      wS[qi][1] = (float)(r1 / sum);
      wS[qi][2] = (float)(r2 / sum);
      iS[qi][0] = I0; iS[qi][1] = I1; iS[qi][2] = I2;
    }
  }
  __syncthreads();

  // ---- phase 2: interp, one (query, 32-channel group) per lane ----
  int wv = tid >> 6, lane = tid & 63;
  int q = wv * 8 + (lane >> 3);    // local query 0..31
  int cg = lane & 7;               // channel group: ch [cg*32, cg*32+32)
  int n = n0 + q;
  int i0 = iS[q][0], i1 = iS[q][1], i2 = iS[q][2];
  float w0 = wS[q][0], w1 = wS[q][1], w2 = wS[q][2];
  const u16* p2b = p2t + (size_t)b * S_ * D2_;
  const u16* r0p = p2b + (size_t)i0 * D2_ + cg * 32;
  const u16* r1p = p2b + (size_t)i1 * D2_ + cg * 32;
  const u16* r2p = p2b + (size_t)i2 * D2_ + cg * 32;
  u16* xrow = xq + (size_t)(b * N_ + n) * XQ_P;
#pragma unroll
  for (int j = 0; j < 8; ++j) {
    ushort4 a = *(const ushort4*)(r0p + j * 4);
    ushort4 e = *(const ushort4*)(r1p + j * 4);
    ushort4 c = *(const ushort4*)(r2p + j * 4);
    ushort4 v;
    v.x = f2b((w0 * b2f(a.x) + w1 * b2f(e.x)) + w2 * b2f(c.x));
    v.y = f2b((w0 * b2f(a.y) + w1 * b2f(e.y)) + w2 * b2f(c.y));
    v.z = f2b((w0 * b2f(a.z) + w1 * b2f(e.z)) + w2 * b2f(c.z));
    v.w = f2b((w0 * b2f(a.w) + w1 * b2f(e.w)) + w2 * b2f(c.w));
    *(ushort4*)(xrow + cg * 32 + j * 4) = v;
  }
  if (cg == 0) {
    const float* lpb = last_pred + (size_t)b * S_ * OC_;
    u16 pv[16];
#pragma unroll
    for (int c = 0; c < 16; ++c) pv[c] = 0;
#pragma unroll
    for (int c = 0; c < OC_; ++c) {
      float l0 = lpb[(size_t)i0 * OC_ + c];
      float l1 = lpb[(size_t)i1 * OC_ + c];
      float l2 = lpb[(size_t)i2 * OC_ + c];
      pv[c] = f2b((w0 * l0 + w1 * l1) + w2 * l2);
    }
#pragma unroll
    for (int c4 = 0; c4 < 4; ++c4) {
      *(ushort4*)(xrow + 256 + c4 * 4) =
          make_ushort4(pv[c4 * 4], pv[c4 * 4 + 1], pv[c4 * 4 + 2], pv[c4 * 4 + 3]);
    }
  }
}

// ---------------------------------------------------------------------------
// gemm_kernel: pure compute phase. Round-7: warm-touch the block's xq tile
// at kernel entry (one dword per thread, kept alive via empty asm) so the
// stage-1 xq reads hit L2/L1 instead of paying HBM latency after the
// stage-0 barrier.
// ---------------------------------------------------------------------------
__device__ __forceinline__ void gemm32(const u16* __restrict__ W, const u16* xb,
                                       int l15, int lq, int wv, f32x4 acc[2][2]) {
#pragma unroll
  for (int mtl = 0; mtl < 2; ++mtl) {
    acc[mtl][0] = (f32x4){0.f, 0.f, 0.f, 0.f};
    acc[mtl][1] = (f32x4){0.f, 0.f, 0.f, 0.f};
  }
#pragma unroll
  for (int ks = 0; ks < 4; ++ks) {
    int ko = ks * 32 + lq * 8;
    s16x8 b0 = *(const s16x8*)(xb + l15 * 136 + ko);
    s16x8 b1 = *(const s16x8*)(xb + (16 + l15) * 136 + ko);
#pragma unroll
    for (int mtl = 0; mtl < 2; ++mtl) {
      s16x8 a = *(const s16x8*)(W + (size_t)((wv * 2 + mtl) * 16 + l15) * 128 + ko);
      acc[mtl][0] = MFMA16(a, b0, acc[mtl][0]);
      acc[mtl][1] = MFMA16(a, b1, acc[mtl][1]);
    }
  }
}

__global__ __launch_bounds__(256, 4) void gemm_kernel(
    const float* __restrict__ points1, const u16* __restrict__ xq,
    const u16* __restrict__ Wf,
    const u16* __restrict__ W1, const u16* __restrict__ W2,
    const u16* __restrict__ W3, const u16* __restrict__ Wp2,
    const float* __restrict__ st, float* __restrict__ out) {
  __shared__ __align__(16) u16 xb0[32 * 136];
  __shared__ __align__(16) u16 xb1[32 * 136];
  int b = blockIdx.y;
  int n0 = blockIdx.x * 32;
  int tid = threadIdx.x;
  int wv = tid >> 6, lane = tid & 63;
  int l15 = lane & 15, lq = lane >> 4;
  f32x4 acc[2][2];

  // ---- warm L2 for this block's xq tile (32 rows x 544 B = 17408 B) ----
  {
    const char* base = (const char*)(xq + (size_t)(b * N_ + n0) * XQ_P);
    u32 t = *(const u32*)(base + tid * 68);   // 256 * 68 = 17408
    asm volatile("" :: "v"(t));
  }

  // ---- stage 0: stage points1 tile [c=128][n=32] -> xb1[n][c] bf16 ----
  {
    int n4 = (tid & 7) * 4;
    int cb = tid >> 3;             // 0..31
    const float* p1b = points1 + (size_t)b * C_ * N_;
#pragma unroll
    for (int rep = 0; rep < 4; ++rep) {
      int c = cb + rep * 32;
      float4 v = *(const float4*)(p1b + (size_t)c * N_ + n0 + n4);
      xb1[(n4 + 0) * 136 + c] = f2b(v.x);
      xb1[(n4 + 1) * 136 + c] = f2b(v.y);
      xb1[(n4 + 2) * 136 + c] = f2b(v.z);
      xb1[(n4 + 3) * 136 + c] = f2b(v.w);
    }
  }
  __syncthreads();

  // ---- stage 1: fuse (K=416): k<128 from xb1 (staged points1), rest xq ----
#pragma unroll
  for (int mtl = 0; mtl < 2; ++mtl) {
    acc[mtl][0] = (f32x4){0.f, 0.f, 0.f, 0.f};
    acc[mtl][1] = (f32x4){0.f, 0.f, 0.f, 0.f};
  }
  {
#pragma unroll 2
    for (int ks = 0; ks < 4; ++ks) {
      int ko = ks * 32 + lq * 8;
      s16x8 bf0 = *(const s16x8*)(&xb1[l15 * 136 + ko]);
      s16x8 bf1 = *(const s16x8*)(&xb1[(16 + l15) * 136 + ko]);
#pragma unroll
      for (int mtl = 0; mtl < 2; ++mtl) {
        s16x8 a = *(const s16x8*)(Wf + (size_t)((wv * 2 + mtl) * 16 + l15) * KP_ + ko);
        acc[mtl][0] = MFMA16(a, bf0, acc[mtl][0]);
        acc[mtl][1] = MFMA16(a, bf1, acc[mtl][1]);
      }
    }
    const u16* qrow0 = xq + ((size_t)(b * N_ + n0 + l15)) * XQ_P;
    const u16* qrow1 = qrow0 + (size_t)16 * XQ_P;
#pragma unroll 3
    for (int ks = 0; ks < 9; ++ks) {
      int col = ks * 32 + lq * 8;
      s16x8 bf0 = {0, 0, 0, 0, 0, 0, 0, 0};
      s16x8 bf1 = {0, 0, 0, 0, 0, 0, 0, 0};
      if (ks < 8 || lq < 2) {     // cols >= 272 are implicit zeros (W also 0)
        bf0 = *(const s16x8*)(qrow0 + col);
        bf1 = *(const s16x8*)(qrow1 + col);
      }
#pragma unroll
      for (int mtl = 0; mtl < 2; ++mtl) {
        s16x8 a = *(const s16x8*)(Wf + (size_t)((wv * 2 + mtl) * 16 + l15) * KP_ + 128 + col);
        acc[mtl][0] = MFMA16(a, bf0, acc[mtl][0]);
        acc[mtl][1] = MFMA16(a, bf1, acc[mtl][1]);
      }
    }
  }
  __syncthreads();   // xb1 reads done (stage 2 will overwrite it)
#pragma unroll
  for (int mtl = 0; mtl < 2; ++mtl) {
    int m4 = (wv * 2 + mtl) * 16 + lq * 4;
    f32x4 sc = *(const f32x4*)(st + 0 * 256 + m4);
    f32x4 bi = *(const f32x4*)(st + 0 * 256 + 128 + m4);
#pragma unroll
    for (int nt = 0; nt < 2; ++nt) {
      int n_l = nt * 16 + l15;
      ushort4 v;
      v.x = f2b(fmaxf(acc[mtl][nt][0] * sc[0] + bi[0], 0.f));
      v.y = f2b(fmaxf(acc[mtl][nt][1] * sc[1] + bi[1], 0.f));
      v.z = f2b(fmaxf(acc[mtl][nt][2] * sc[2] + bi[2], 0.f));
      v.w = f2b(fmaxf(acc[mtl][nt][3] * sc[3] + bi[3], 0.f));
      *(ushort4*)(&xb0[n_l * 136 + m4]) = v;
    }
  }
  __syncthreads();

  // ---- stage 2: ext1 (K=128), xb0 -> xb1 ----
  gemm32(W1, xb0, l15, lq, wv, acc);
#pragma unroll
  for (int mtl = 0; mtl < 2; ++mtl) {
    int m4 = (wv * 2 + mtl) * 16 + lq * 4;
    f32x4 sc = *(const f32x4*)(st + 1 * 256 + m4);
    f32x4 bi = *(const f32x4*)(st + 1 * 256 + 128 + m4);
#pragma unroll
    for (int nt = 0; nt < 2; ++nt) {
      int n_l = nt * 16 + l15;
      ushort4 v;
      v.x = f2b(fmaxf(acc[mtl][nt][0] * sc[0] + bi[0], 0.f));
      v.y = f2b(fmaxf(acc[mtl][nt][1] * sc[1] + bi[1], 0.f));
      v.z = f2b(fmaxf(acc[mtl][nt][2] * sc[2] + bi[2], 0.f));
      v.w = f2b(fmaxf(acc[mtl][nt][3] * sc[3] + bi[3], 0.f));
      *(ushort4*)(&xb1[n_l * 136 + m4]) = v;
    }
  }
  __syncthreads();

  // ---- stage 3: ext2 (K=128), xb1 -> xb0, + residual(xb0), store out0 ----
  gemm32(W2, xb1, l15, lq, wv, acc);
#pragma unroll
  for (int mtl = 0; mtl < 2; ++mtl) {
    int m4 = (wv * 2 + mtl) * 16 + lq * 4;
    f32x4 sc = *(const f32x4*)(st + 2 * 256 + m4);
    f32x4 bi = *(const f32x4*)(st + 2 * 256 + 128 + m4);
#pragma unroll
    for (int nt = 0; nt < 2; ++nt) {
      int n_l = nt * 16 + l15;
      int n_g = n0 + n_l;
      ushort4 xp = *(const ushort4*)(&xb0[n_l * 136 + m4]);
      float v0 = fmaxf(acc[mtl][nt][0] * sc[0] + bi[0] + b2f(xp.x), 0.f);
      float v1 = fmaxf(acc[mtl][nt][1] * sc[1] + bi[1] + b2f(xp.y), 0.f);
      float v2 = fmaxf(acc[mtl][nt][2] * sc[2] + bi[2] + b2f(xp.z), 0.f);
      float v3 = fmaxf(acc[mtl][nt][3] * sc[3] + bi[3] + b2f(xp.w), 0.f);
      ushort4 v;
      v.x = f2b(v0); v.y = f2b(v1); v.z = f2b(v2); v.w = f2b(v3);
      *(ushort4*)(&xb0[n_l * 136 + m4]) = v;
      out[((size_t)(b * C_ + m4 + 0)) * N_ + n_g] = v0;
      out[((size_t)(b * C_ + m4 + 1)) * N_ + n_g] = v1;
      out[((size_t)(b * C_ + m4 + 2)) * N_ + n_g] = v2;
      out[((size_t)(b * C_ + m4 + 3)) * N_ + n_g] = v3;
    }
  }
  __syncthreads();

  // ---- stage 4: pred1 (K=128), xb0 -> xb1, store out1 ([B][N][128]) ----
  gemm32(W3, xb0, l15, lq, wv, acc);
  {
    float* out1 = out + (size_t)B_ * C_ * N_;
#pragma unroll
    for (int mtl = 0; mtl < 2; ++mtl) {
      int m4 = (wv * 2 + mtl) * 16 + lq * 4;
      f32x4 sc = *(const f32x4*)(st + 3 * 256 + m4);
      f32x4 bi = *(const f32x4*)(st + 3 * 256 + 128 + m4);
#pragma unroll
      for (int nt = 0; nt < 2; ++nt) {
        int n_l = nt * 16 + l15;
        int n_g = n0 + n_l;
        float v0 = fmaxf(acc[mtl][nt][0] * sc[0] + bi[0], 0.f);
        float v1 = fmaxf(acc[mtl][nt][1] * sc[1] + bi[1], 0.f);
        float v2 = fmaxf(acc[mtl][nt][2] * sc[2] + bi[2], 0.f);
        float v3 = fmaxf(acc[mtl][nt][3] * sc[3] + bi[3], 0.f);
        ushort4 v;
        v.x = f2b(v0); v.y = f2b(v1); v.z = f2b(v2); v.w = f2b(v3);
        *(ushort4*)(&xb1[n_l * 136 + m4]) = v;
        float4 o4 = make_float4(v0, v1, v2, v3);
        *(float4*)(out1 + ((size_t)(b * N_ + n_g)) * 128 + m4) = o4;
      }
    }
  }
  __syncthreads();

  // ---- stage 5: pred2 (M=13 pad 16, K=128): waves 0,1 each do one nt ----
  if (wv < 2) {
    f32x4 a2 = (f32x4){0.f, 0.f, 0.f, 0.f};
#pragma unroll
    for (int ks = 0; ks < 4; ++ks) {
      int ko = ks * 32 + lq * 8;
      s16x8 b0 = *(const s16x8*)(&xb1[(wv * 16 + l15) * 136 + ko]);
      s16x8 a = *(const s16x8*)(Wp2 + (size_t)l15 * 128 + ko);
      a2 = MFMA16(a, b0, a2);
    }
    float* out2 = out + (size_t)B_ * C_ * N_ + (size_t)B_ * N_ * 128;
    f32x4 sc = *(const f32x4*)(st + 4 * 256 + lq * 4);
    f32x4 bi = *(const f32x4*)(st + 4 * 256 + 128 + lq * 4);
    int n_g = n0 + wv * 16 + l15;
#pragma unroll
    for (int r = 0; r < 4; ++r) {
      int m = lq * 4 + r;
      if (m < OC_) {
        out2[((size_t)(b * N_ + n_g)) * OC_ + m] =
            fmaxf(a2[r] * sc[r] + bi[r], 0.f);
      }
    }
  }
}

// ---------------------------------------------------------------------------
extern "C" void kernel_launch(void* const* d_in, const int* in_sizes, int n_in,
                              void* d_out, int out_size, void* d_ws, size_t ws_size,
                              hipStream_t stream) {
  const float* xyz1      = (const float*)d_in[0];
  const float* xyz2      = (const float*)d_in[1];
  const float* points1   = (const float*)d_in[2];
  const float* points2   = (const float*)d_in[3];
  const float* last_pred = (const float*)d_in[4];
  const float* fuse_W    = (const float*)d_in[5];
  const float* fuse_b    = (const float*)d_in[6];
  const float* fuse_bn   = (const float*)d_in[7];
  const float* ext1_W    = (const float*)d_in[8];
  const float* ext1_b    = (const float*)d_in[9];
  const float* ext1_bn   = (const float*)d_in[10];
  const float* ext2_W    = (const float*)d_in[11];
  const float* ext2_b    = (const float*)d_in[12];
  const float* ext2_bn   = (const float*)d_in[13];
  const float* pred1_W   = (const float*)d_in[14];
  const float* pred1_b   = (const float*)d_in[15];
  const float* pred1_bn  = (const float*)d_in[16];
  const float* pred2_W   = (const float*)d_in[17];
  const float* pred2_b   = (const float*)d_in[18];
  const float* pred2_bn  = (const float*)d_in[19];

  char* ws = (char*)d_ws;
  u16*   p2t  = (u16*)(ws + 0);                // 2*4096*256*2    =  4,194,304
  u16*   cand = (u16*)(ws + 4194304);          // 2*16*16384*4*2  =  4,194,304
  u16*   Wf   = (u16*)(ws + 8388608);          // 128*416*2       =    106,496
  u16*   W1   = (u16*)(ws + 8495104);          // 128*128*2       =     32,768
  u16*   W2   = (u16*)(ws + 8527872);          //                       32,768
  u16*   W3   = (u16*)(ws + 8560640);          //                       32,768
  u16*   Wp2  = (u16*)(ws + 8593408);          // 16*128*2        =      4,096
  float* st   = (float*)(ws + 8597504);        // 5*256*4         =      5,120
  u16*   xq   = (u16*)(ws + 8602624);          // 2*16384*272*2   = 17,825,792
                                               // total 26,428,416 B

  setup_scan_kernel<<<dim3(1600), dim3(256), 0, stream>>>(
      xyz1, xyz2, points2,
      fuse_W, fuse_b, fuse_bn, ext1_W, ext1_b, ext1_bn, ext2_W, ext2_b, ext2_bn,
      pred1_W, pred1_b, pred1_bn, pred2_W, pred2_b, pred2_bn,
      cand, p2t, Wf, W1, W2, W3, Wp2, st);

  interp_kernel<<<dim3(1024), dim3(256), 0, stream>>>(
      xyz1, xyz2, cand, p2t, last_pred, xq);

  gemm_kernel<<<dim3(N_ / 32, B_), dim3(256), 0, stream>>>(
      points1, xq, Wf, W1, W2, W3, Wp2, st, (float*)d_out);
}